// Round 2
// baseline (883.259 us; speedup 1.0000x reference)
//
#include <hip/hip_runtime.h>

typedef unsigned short u16;
typedef unsigned int u32;
typedef __attribute__((ext_vector_type(8))) short bf16x8;
typedef __attribute__((ext_vector_type(4))) float f32x4;

#define H_ 200
#define W_ 176
#define HW_ (200 * 176)
#define D0_ 41
#define D1_ 20
#define D2_ 9
#define B_ 2

__device__ __forceinline__ float bf2f(u16 v) {
  union { u32 u; float f; } c; c.u = ((u32)v) << 16; return c.f;
}
__device__ __forceinline__ u16 f2bf(float f) {
  union { float f; u32 u; } c; c.f = f;
  u32 u = c.u;
  u32 r = (u + 0x7fffu + ((u >> 16) & 1u)) >> 16;
  return (u16)r;
}

// ---- dtype detector: flag=1 if inputs are bf16, 0 if fp32 ----
// fp32 data read as u16 pairs: even-indexed halves are low mantissa bits ->
// random bf16 exponent (~12% in [0x70,0x8F]). Real bf16 N(0,1) data: ~100%.
__global__ void k_detect(const u16* __restrict__ in, int* __restrict__ flag) {
  __shared__ int cnt;
  int t = threadIdx.x;
  if (t == 0) cnt = 0;
  __syncthreads();
  u16 v = in[2 * t];
  int e = (v >> 7) & 0xFF;
  if (e >= 0x70 && e <= 0x8F) atomicAdd(&cnt, 1);
  __syncthreads();
  if (t == 0) *flag = (cnt >= 128) ? 1 : 0;
}

// ---- init: counters + stats ----
__global__ void k_init(int* ctrl, float* stats, int N) {
  int t = threadIdx.x;
  if (t == 0) { ctrl[0] = N; ctrl[1] = 0; ctrl[2] = 0; }
  for (int i = t; i < 768; i += 256) stats[i] = 0.f;
}

__global__ void k_fill_neg1(int* __restrict__ p, int n) {
  int i = blockIdx.x * blockDim.x + threadIdx.x;
  if (i < n) p[i] = -1;
}

__global__ void k_scatter_idx(const int* __restrict__ coors, int N, int* __restrict__ idx0) {
  int i = blockIdx.x * blockDim.x + threadIdx.x;
  if (i >= N) return;
  int b = coors[i * 4], z = coors[i * 4 + 1], y = coors[i * 4 + 2], x = coors[i * 4 + 3];
  idx0[((size_t)(b * D0_ + z) * H_ + y) * W_ + x] = i;
}

// ---- convert feats to bf16 (dual dtype) ----
__global__ void k_cvt(const void* __restrict__ in, u16* __restrict__ out, int n,
                      const int* __restrict__ flag) {
  int i = blockIdx.x * blockDim.x + threadIdx.x;
  if (i >= n) return;
  out[i] = (*flag) ? ((const u16*)in)[i] : f2bf(((const float*)in)[i]);
}

// ---- repack weights (NOFF,K,64) -> fragment order [o][ks][nt][lane][8] ----
__global__ void k_repack(const void* __restrict__ w, u16* __restrict__ frag, int K, int NOFF,
                         const int* __restrict__ flag) {
  int t = blockIdx.x * blockDim.x + threadIdx.x;
  int KS = K / 32;
  int total = NOFF * KS * 2048;
  if (t >= total) return;
  int j = t & 7;
  int lane = (t >> 3) & 63;
  int nt = (t >> 9) & 3;
  int rest = t >> 11;
  int ks = rest % KS;
  int o = rest / KS;
  int k = ks * 32 + (lane >> 4) * 8 + j;
  int n = nt * 16 + (lane & 15);
  size_t idx = ((size_t)o * K + k) * 64 + n;
  frag[t] = (*flag) ? ((const u16*)w)[idx] : f2bf(((const float*)w)[idx]);
}

// ---- 27-neighborhood table ----
__global__ void k_nbr27(const int* __restrict__ coords, const int* __restrict__ cntp,
                        const int* __restrict__ idxmap, int D, int* __restrict__ nbr, int cap) {
  int t = blockIdx.x * blockDim.x + threadIdx.x;
  if (t >= cap * 27) return;
  int i = t / 27, o = t - i * 27;
  if (i >= *cntp) return;
  int b = coords[i * 4], z = coords[i * 4 + 1], y = coords[i * 4 + 2], x = coords[i * 4 + 3];
  int nz = z + o / 9 - 1;
  int ny = y + (o / 3) % 3 - 1;
  int nx = x + o % 3 - 1;
  int j = -1;
  if (nz >= 0 && nz < D && ny >= 0 && ny < H_ && nx >= 0 && nx < W_)
    j = idxmap[((size_t)(b * D + nz) * H_ + ny) * W_ + nx];
  nbr[t] = j;
}

// ---- strided z-downsample: occupancy + compaction + 3-tap neighbor table ----
__global__ void k_down(const int* __restrict__ idxin, int Din, int Dout,
                       int* idxout, int* __restrict__ coords_out, int* __restrict__ nbrz,
                       int* cntp) {
  int pos = blockIdx.x * blockDim.x + threadIdx.x;
  int total = B_ * Dout * HW_;
  if (pos >= total) return;
  int x = pos % W_;
  int y = (pos / W_) % H_;
  int oz = (pos / HW_) % Dout;
  int b = pos / (HW_ * Dout);
  size_t bse = ((size_t)(b * Din + 2 * oz) * H_ + y) * W_ + x;
  int j0 = idxin[bse];
  int j1 = idxin[bse + HW_];
  int j2 = idxin[bse + 2 * (size_t)HW_];
  int id = -1;
  if (j0 >= 0 || j1 >= 0 || j2 >= 0) {
    id = atomicAdd(cntp, 1);
    coords_out[id * 4 + 0] = b;
    coords_out[id * 4 + 1] = oz;
    coords_out[id * 4 + 2] = y;
    coords_out[id * 4 + 3] = x;
    nbrz[id * 3 + 0] = j0;
    nbrz[id * 3 + 1] = j1;
    nbrz[id * 3 + 2] = j2;
  }
  if (idxout) idxout[pos] = id;
}

// ---- gathered MFMA conv: out[i] = sum_o feats[nbr[i][o]] @ W_o ----
template <int K, int NOFF>
__global__ __launch_bounds__(256) void k_conv(const u16* __restrict__ feats,
                                              const int* __restrict__ nbr,
                                              const u16* __restrict__ wfrag,
                                              float* __restrict__ out,
                                              const int* __restrict__ cntp) {
  constexpr int KS = K / 32;
  int cnt = *cntp;
  int lane = threadIdx.x & 63;
  int base = (blockIdx.x * 4 + (threadIdx.x >> 6)) * 16;
  if (base >= cnt) return;
  int am = lane & 15;   // A row (point within tile); also C col (channel low 4 bits)
  int kr = lane >> 4;   // A k-group; C row group
  int pt = base + am;
  bool vpt = pt < cnt;
  f32x4 acc0 = {0.f, 0.f, 0.f, 0.f};
  f32x4 acc1 = acc0, acc2 = acc0, acc3 = acc0;
  for (int o = 0; o < NOFF; ++o) {
    int j = vpt ? nbr[pt * NOFF + o] : -1;
    const u16* bw = wfrag + (size_t)o * (KS * 2048) + lane * 8;
#pragma unroll
    for (int ks = 0; ks < KS; ++ks) {
      bf16x8 a = {0, 0, 0, 0, 0, 0, 0, 0};
      if (j >= 0) a = *(const bf16x8*)(feats + (size_t)j * K + ks * 32 + kr * 8);
      const u16* bwk = bw + ks * 2048;
      acc0 = __builtin_amdgcn_mfma_f32_16x16x32_bf16(a, *(const bf16x8*)(bwk), acc0, 0, 0, 0);
      acc1 = __builtin_amdgcn_mfma_f32_16x16x32_bf16(a, *(const bf16x8*)(bwk + 512), acc1, 0, 0, 0);
      acc2 = __builtin_amdgcn_mfma_f32_16x16x32_bf16(a, *(const bf16x8*)(bwk + 1024), acc2, 0, 0, 0);
      acc3 = __builtin_amdgcn_mfma_f32_16x16x32_bf16(a, *(const bf16x8*)(bwk + 1536), acc3, 0, 0, 0);
    }
  }
#pragma unroll
  for (int r = 0; r < 4; ++r) {
    int po = base + kr * 4 + r;
    if (po < cnt) {
      float* op = out + (size_t)po * 64 + am;
      op[0] = acc0[r];
      op[16] = acc1[r];
      op[32] = acc2[r];
      op[48] = acc3[r];
    }
  }
}

// ---- BN stats: per-channel sum / sumsq ----
__global__ void k_stats(const float* __restrict__ x, const int* __restrict__ cntp,
                        float* __restrict__ stats) {
  int cnt = *cntp;
  int c = threadIdx.x & 63, g = threadIdx.x >> 6;
  float s = 0.f, ss = 0.f;
  for (int i = blockIdx.x * 4 + g; i < cnt; i += gridDim.x * 4) {
    float v = x[(size_t)i * 64 + c];
    s += v;
    ss += v * v;
  }
  __shared__ float ls[4][64], lq[4][64];
  ls[g][c] = s;
  lq[g][c] = ss;
  __syncthreads();
  if (g == 0) {
    s = ls[0][c] + ls[1][c] + ls[2][c] + ls[3][c];
    ss = lq[0][c] + lq[1][c] + lq[2][c] + lq[3][c];
    atomicAdd(&stats[c], s);
    atomicAdd(&stats[64 + c], ss);
  }
}

// ---- BN normalize + ReLU -> bf16 (intermediate layers; gamma/beta dual dtype) ----
__global__ void k_norm(const float* __restrict__ x, const int* __restrict__ cntp,
                       const float* __restrict__ stats, const void* __restrict__ gamma,
                       const void* __restrict__ beta, u16* __restrict__ y,
                       const int* __restrict__ flag) {
  int cnt = *cntp;
  int t = blockIdx.x * blockDim.x + threadIdx.x;
  int i = t >> 6, c = t & 63;
  if (i >= cnt) return;
  int bf = *flag;
  float g = bf ? bf2f(((const u16*)gamma)[c]) : ((const float*)gamma)[c];
  float bb = bf ? bf2f(((const u16*)beta)[c]) : ((const float*)beta)[c];
  float cf = (float)(cnt > 0 ? cnt : 1);
  float mean = stats[c] / cf;
  float var = stats[64 + c] / cf - mean * mean;
  float inv = rsqrtf(var + 1e-3f);
  float v = (x[(size_t)i * 64 + c] - mean) * inv * g + bb;
  y[(size_t)i * 64 + c] = f2bf(fmaxf(v, 0.f));
}

// ---- zero d_out; byte count depends on output dtype ----
__global__ void k_zero_out(uint4* __restrict__ p, int n_fp32_chunks, const int* __restrict__ flag) {
  int i = blockIdx.x * blockDim.x + threadIdx.x;
  int n = (*flag) ? (n_fp32_chunks >> 1) : n_fp32_chunks;
  if (i < n) {
    uint4 z;
    z.x = 0; z.y = 0; z.z = 0; z.w = 0;
    p[i] = z;
  }
}

// ---- final BN + ReLU fused with dense scatter (dual output dtype) ----
__global__ void k_norm_scatter(const float* __restrict__ x, const int* __restrict__ cntp,
                               const float* __restrict__ stats, const void* __restrict__ gamma,
                               const void* __restrict__ beta, const int* __restrict__ coords,
                               void* __restrict__ out, const int* __restrict__ flag) {
  int t = blockIdx.x * blockDim.x + threadIdx.x;
  int i = t >> 6, c = t & 63;
  int cnt = *cntp;
  if (i >= cnt) return;
  int bf = *flag;
  float g = bf ? bf2f(((const u16*)gamma)[c]) : ((const float*)gamma)[c];
  float bb = bf ? bf2f(((const u16*)beta)[c]) : ((const float*)beta)[c];
  float cf = (float)(cnt > 0 ? cnt : 1);
  float mean = stats[c] / cf;
  float var = stats[64 + c] / cf - mean * mean;
  float inv = rsqrtf(var + 1e-3f);
  float v = fmaxf((x[(size_t)i * 64 + c] - mean) * inv * g + bb, 0.f);
  int b = coords[i * 4], oz = coords[i * 4 + 1], yy = coords[i * 4 + 2], xx = coords[i * 4 + 3];
  size_t oidx = (((size_t)(b * 64 + c) * D2_ + oz) * H_ + yy) * W_ + xx;
  if (bf) ((u16*)out)[oidx] = f2bf(v);
  else ((float*)out)[oidx] = v;
}

extern "C" void kernel_launch(void* const* d_in, const int* in_sizes, int n_in,
                              void* d_out, int out_size, void* d_ws, size_t ws_size,
                              hipStream_t stream) {
  const int N = in_sizes[0] / 128;
  const int cap1 = 2 * N + 8;
  const int cap2 = 4 * N + 8;

  char* ws = (char*)d_ws;
  size_t off = 0;
  auto alloc = [&](size_t bytes) -> void* {
    size_t o = off;
    off = (off + bytes + 255) & ~(size_t)255;
    return (void*)(ws + o);
  };

  int* ctrl = (int*)alloc(16);  // [0]=cnt0(=N) [1]=cnt1 [2]=cnt2
  int* flag = (int*)alloc(16);  // dtype flag: 1=bf16, 0=fp32
  float* stats = (float*)alloc(768 * 4);
  int* idx0 = (int*)alloc((size_t)B_ * D0_ * HW_ * 4);
  int* idx1 = (int*)alloc((size_t)B_ * D1_ * HW_ * 4);
  int* nbr0 = (int*)alloc((size_t)N * 27 * 4);
  int* nbr1 = (int*)alloc((size_t)cap1 * 27 * 4);
  int* nbrz1 = (int*)alloc((size_t)cap1 * 3 * 4);
  int* nbrz2 = (int*)alloc((size_t)cap2 * 3 * 4);
  int* coords1 = (int*)alloc((size_t)cap1 * 4 * 4);
  int* coords2 = (int*)alloc((size_t)cap2 * 4 * 4);
  float* xbuf = (float*)alloc((size_t)cap2 * 64 * 4);
  u16* fb = (u16*)alloc((size_t)N * 128 * 2);   // bf16 feats
  u16* y0 = (u16*)alloc((size_t)N * 64 * 2);
  u16* y1 = (u16*)alloc((size_t)cap1 * 64 * 2);
  u16* y2 = (u16*)alloc((size_t)cap1 * 64 * 2);
  u16* y3 = (u16*)alloc((size_t)cap1 * 64 * 2);
  u16* wf0 = (u16*)alloc((size_t)27 * 4 * 2048 * 2);
  u16* wf1a = (u16*)alloc((size_t)27 * 2 * 2048 * 2);
  u16* wf1b = (u16*)alloc((size_t)27 * 2 * 2048 * 2);
  u16* wfz1 = (u16*)alloc((size_t)3 * 2 * 2048 * 2);
  u16* wfz2 = (u16*)alloc((size_t)3 * 2 * 2048 * 2);

  const int* coors = (const int*)d_in[1];

  auto gr = [](long n) { return dim3((unsigned)((n + 255) / 256)); };

  k_detect<<<1, 256, 0, stream>>>((const u16*)d_in[0], flag);
  k_init<<<1, 256, 0, stream>>>(ctrl, stats, N);

  int nIdx0 = B_ * D0_ * HW_;
  k_fill_neg1<<<gr(nIdx0), 256, 0, stream>>>(idx0, nIdx0);
  k_scatter_idx<<<gr(N), 256, 0, stream>>>(coors, N, idx0);

  k_cvt<<<gr((long)N * 128), 256, 0, stream>>>(d_in[0], fb, N * 128, flag);
  k_repack<<<gr(27 * 4 * 2048), 256, 0, stream>>>(d_in[3], wf0, 128, 27, flag);
  k_repack<<<gr(27 * 2 * 2048), 256, 0, stream>>>(d_in[9], wf1a, 64, 27, flag);
  k_repack<<<gr(27 * 2 * 2048), 256, 0, stream>>>(d_in[12], wf1b, 64, 27, flag);
  k_repack<<<gr(3 * 2 * 2048), 256, 0, stream>>>(d_in[6], wfz1, 64, 3, flag);
  k_repack<<<gr(3 * 2 * 2048), 256, 0, stream>>>(d_in[15], wfz2, 64, 3, flag);

  int n16 = out_size / 4;  // uint4 chunks if output were fp32
  k_zero_out<<<gr(n16), 256, 0, stream>>>((uint4*)d_out, n16, flag);

  // ---- level 0: subm conv (128 -> 64) + BN/ReLU ----
  k_nbr27<<<gr((long)N * 27), 256, 0, stream>>>(coors, ctrl + 0, idx0, D0_, nbr0, N);
  k_conv<128, 27><<<dim3((N + 63) / 64), 256, 0, stream>>>(fb, nbr0, wf0, xbuf, ctrl + 0);
  k_stats<<<512, 256, 0, stream>>>(xbuf, ctrl + 0, stats + 0);
  k_norm<<<gr((long)N * 64), 256, 0, stream>>>(xbuf, ctrl + 0, stats + 0, d_in[4], d_in[5], y0, flag);

  // ---- downsample z: D0 -> D1 ----
  int nd1 = B_ * D1_ * HW_;
  k_down<<<gr(nd1), 256, 0, stream>>>(idx0, D0_, D1_, idx1, coords1, nbrz1, ctrl + 1);
  k_conv<64, 3><<<dim3((cap1 + 63) / 64), 256, 0, stream>>>(y0, nbrz1, wfz1, xbuf, ctrl + 1);
  k_stats<<<512, 256, 0, stream>>>(xbuf, ctrl + 1, stats + 128);
  k_norm<<<gr((long)cap1 * 64), 256, 0, stream>>>(xbuf, ctrl + 1, stats + 128, d_in[7], d_in[8], y1, flag);

  // ---- level 1: subm conv a ----
  k_nbr27<<<gr((long)cap1 * 27), 256, 0, stream>>>(coords1, ctrl + 1, idx1, D1_, nbr1, cap1);
  k_conv<64, 27><<<dim3((cap1 + 63) / 64), 256, 0, stream>>>(y1, nbr1, wf1a, xbuf, ctrl + 1);
  k_stats<<<512, 256, 0, stream>>>(xbuf, ctrl + 1, stats + 256);
  k_norm<<<gr((long)cap1 * 64), 256, 0, stream>>>(xbuf, ctrl + 1, stats + 256, d_in[10], d_in[11], y2, flag);

  // ---- level 1: subm conv b ----
  k_conv<64, 27><<<dim3((cap1 + 63) / 64), 256, 0, stream>>>(y2, nbr1, wf1b, xbuf, ctrl + 1);
  k_stats<<<512, 256, 0, stream>>>(xbuf, ctrl + 1, stats + 384);
  k_norm<<<gr((long)cap1 * 64), 256, 0, stream>>>(xbuf, ctrl + 1, stats + 384, d_in[13], d_in[14], y3, flag);

  // ---- downsample z: D1 -> D2 ----
  int nd2 = B_ * D2_ * HW_;
  k_down<<<gr(nd2), 256, 0, stream>>>(idx1, D1_, D2_, (int*)nullptr, coords2, nbrz2, ctrl + 2);
  k_conv<64, 3><<<dim3((cap2 + 63) / 64), 256, 0, stream>>>(y3, nbrz2, wfz2, xbuf, ctrl + 2);
  k_stats<<<512, 256, 0, stream>>>(xbuf, ctrl + 2, stats + 512);

  // ---- final BN + ReLU + dense scatter ----
  k_norm_scatter<<<gr((long)cap2 * 64), 256, 0, stream>>>(xbuf, ctrl + 2, stats + 512,
                                                          d_in[16], d_in[17], coords2,
                                                          d_out, flag);
}

// Round 3
// 540.993 us; speedup vs baseline: 1.6327x; 1.6327x over previous
//
#include <hip/hip_runtime.h>

typedef unsigned short u16;
typedef unsigned int u32;
typedef unsigned long long u64;
typedef __attribute__((ext_vector_type(8))) short bf16x8;
typedef __attribute__((ext_vector_type(4))) float f32x4;

#define H_ 200
#define W_ 176
#define HW_ (200 * 176)
#define D0_ 41
#define D1_ 20
#define D2_ 9
#define B_ 2

__device__ __forceinline__ float bf2f(u16 v) {
  union { u32 u; float f; } c; c.u = ((u32)v) << 16; return c.f;
}
__device__ __forceinline__ u16 f2bf(float f) {
  union { float f; u32 u; } c; c.f = f;
  u32 u = c.u;
  u32 r = (u + 0x7fffu + ((u >> 16) & 1u)) >> 16;
  return (u16)r;
}

// ---- dtype detector: flag=1 if inputs are bf16, 0 if fp32 ----
__global__ void k_detect(const u16* __restrict__ in, int* __restrict__ flag) {
  __shared__ int cnt;
  int t = threadIdx.x;
  if (t == 0) cnt = 0;
  __syncthreads();
  u16 v = in[2 * t];
  int e = (v >> 7) & 0xFF;
  if (e >= 0x70 && e <= 0x8F) atomicAdd(&cnt, 1);
  __syncthreads();
  if (t == 0) *flag = (cnt >= 128) ? 1 : 0;
}

__global__ void k_init(int* ctrl, float* stats, int N) {
  int t = threadIdx.x;
  if (t == 0) { ctrl[0] = N; ctrl[1] = 0; ctrl[2] = 0; }
  for (int i = t; i < 768; i += 256) stats[i] = 0.f;
}

// fill a region with -1 using 16B stores
__global__ void k_fillm1(uint4* __restrict__ p, int n) {
  int i = blockIdx.x * blockDim.x + threadIdx.x;
  if (i < n) {
    uint4 v;
    v.x = 0xFFFFFFFFu; v.y = 0xFFFFFFFFu; v.z = 0xFFFFFFFFu; v.w = 0xFFFFFFFFu;
    p[i] = v;
  }
}

__global__ void k_scatter_idx(const int* __restrict__ coors, int N, int* __restrict__ idx0) {
  int i = blockIdx.x * blockDim.x + threadIdx.x;
  if (i >= N) return;
  int b = coors[i * 4], z = coors[i * 4 + 1], y = coors[i * 4 + 2], x = coors[i * 4 + 3];
  idx0[((size_t)(b * D0_ + z) * H_ + y) * W_ + x] = i;
}

__global__ void k_cvt(const void* __restrict__ in, u16* __restrict__ out, int n,
                      const int* __restrict__ flag) {
  int i = blockIdx.x * blockDim.x + threadIdx.x;
  if (i >= n) return;
  out[i] = (*flag) ? ((const u16*)in)[i] : f2bf(((const float*)in)[i]);
}

// ---- repack weights (NOFF,K,64) -> fragment order [o][ks][nt][lane][8] ----
__global__ void k_repack(const void* __restrict__ w, u16* __restrict__ frag, int K, int NOFF,
                         const int* __restrict__ flag) {
  int t = blockIdx.x * blockDim.x + threadIdx.x;
  int KS = K / 32;
  int total = NOFF * KS * 2048;
  if (t >= total) return;
  int j = t & 7;
  int lane = (t >> 3) & 63;
  int nt = (t >> 9) & 3;
  int rest = t >> 11;
  int ks = rest % KS;
  int o = rest / KS;
  int k = ks * 32 + (lane >> 4) * 8 + j;
  int n = nt * 16 + (lane & 15);
  size_t idx = ((size_t)o * K + k) * 64 + n;
  frag[t] = (*flag) ? ((const u16*)w)[idx] : f2bf(((const float*)w)[idx]);
}

// ---- 27-neighborhood table ----
__global__ void k_nbr27(const int* __restrict__ coords, const int* __restrict__ cntp,
                        const int* __restrict__ idxmap, int D, int* __restrict__ nbr, int cap) {
  int t = blockIdx.x * blockDim.x + threadIdx.x;
  if (t >= cap * 27) return;
  int i = t / 27, o = t - i * 27;
  if (i >= *cntp) return;
  int b = coords[i * 4], z = coords[i * 4 + 1], y = coords[i * 4 + 2], x = coords[i * 4 + 3];
  int nz = z + o / 9 - 1;
  int ny = y + (o / 3) % 3 - 1;
  int nx = x + o % 3 - 1;
  int j = -1;
  if (nz >= 0 && nz < D && ny >= 0 && ny < H_ && nx >= 0 && nx < W_)
    j = idxmap[((size_t)(b * D + nz) * H_ + ny) * W_ + nx];
  nbr[t] = j;
}

// ---- point-driven strided z-downsample (claim + wave-aggregated id alloc) ----
// claim map pre-filled -1; becomes the output-level dense idx map.
__global__ void k_claim(const int* __restrict__ coords, const int* __restrict__ cntp,
                        const int* __restrict__ idxin, int Din, int Dout,
                        int* __restrict__ claim, int* __restrict__ coords_out,
                        int* __restrict__ nbrz, int* __restrict__ outcnt) {
  int i = blockIdx.x * blockDim.x + threadIdx.x;
  int cnt = *cntp;
  bool w0 = false, w1 = false;
  int pos0 = 0, pos1 = 0, oz0 = -1, oz1 = -1;
  int b = 0, z = 0, y = 0, x = 0;
  if (i < cnt) {
    b = coords[i * 4]; z = coords[i * 4 + 1]; y = coords[i * 4 + 2]; x = coords[i * 4 + 3];
    if (z & 1) {
      int oz = (z - 1) >> 1;
      if (oz < Dout) oz0 = oz;
    } else {
      int oz = z >> 1;
      if (oz < Dout) oz0 = oz;
      if (z >= 2) oz1 = oz - 1;   // oz-1 < Dout guaranteed when oz-1 >= 0
    }
    if (oz0 >= 0) {
      pos0 = ((b * Dout + oz0) * H_ + y) * W_ + x;
      w0 = (atomicCAS(&claim[pos0], -1, -2) == -1);
    }
    if (oz1 >= 0) {
      pos1 = ((b * Dout + oz1) * H_ + y) * W_ + x;
      w1 = (atomicCAS(&claim[pos1], -1, -2) == -1);
    }
  }
  u64 m0 = __ballot(w0), m1 = __ballot(w1);
  int c0 = __popcll(m0), c1 = __popcll(m1);
  int lane = threadIdx.x & 63;
  u64 lt = (lane == 63) ? 0x7FFFFFFFFFFFFFFFull : ((1ull << lane) - 1ull);
  int base = 0;
  if (lane == 0 && (c0 + c1) > 0) base = atomicAdd(outcnt, c0 + c1);
  base = __shfl(base, 0);
  if (w0) {
    int id = base + __popcll(m0 & lt);
    claim[pos0] = id;
    coords_out[id * 4 + 0] = b; coords_out[id * 4 + 1] = oz0;
    coords_out[id * 4 + 2] = y; coords_out[id * 4 + 3] = x;
    size_t bse = ((size_t)(b * Din + 2 * oz0) * H_ + y) * W_ + x;
    nbrz[id * 3 + 0] = idxin[bse];
    nbrz[id * 3 + 1] = idxin[bse + HW_];
    nbrz[id * 3 + 2] = idxin[bse + 2 * (size_t)HW_];
  }
  if (w1) {
    int id = base + c0 + __popcll(m1 & lt);
    claim[pos1] = id;
    coords_out[id * 4 + 0] = b; coords_out[id * 4 + 1] = oz1;
    coords_out[id * 4 + 2] = y; coords_out[id * 4 + 3] = x;
    size_t bse = ((size_t)(b * Din + 2 * oz1) * H_ + y) * W_ + x;
    nbrz[id * 3 + 0] = idxin[bse];
    nbrz[id * 3 + 1] = idxin[bse + HW_];
    nbrz[id * 3 + 2] = idxin[bse + 2 * (size_t)HW_];
  }
}

// ---- gathered MFMA conv with nbr/A prefetch + fused BN-stats ----
template <int K, int NOFF>
__global__ __launch_bounds__(256) void k_conv(const u16* __restrict__ feats,
                                              const int* __restrict__ nbr,
                                              const u16* __restrict__ wfrag,
                                              float* __restrict__ out,
                                              const int* __restrict__ cntp,
                                              float* __restrict__ stats) {
  constexpr int KS = K / 32;
  __shared__ float lsum[64], lss[64];
  int cnt = *cntp;
  int t = threadIdx.x;
  if (t < 64) { lsum[t] = 0.f; lss[t] = 0.f; }
  __syncthreads();
  int lane = t & 63;
  int base = (blockIdx.x * 4 + (t >> 6)) * 16;
  bool active = base < cnt;
  int am = lane & 15;   // A row (point in tile); C col (channel low bits)
  int kr = lane >> 4;   // A k-group; C row group
  int pt = base + am;
  bool vpt = active && (pt < cnt);
  f32x4 acc0 = {0.f, 0.f, 0.f, 0.f};
  f32x4 acc1 = acc0, acc2 = acc0, acc3 = acc0;
  if (active) {
    const int* np = nbr + (size_t)pt * NOFF;
    bf16x8 zf = {0, 0, 0, 0, 0, 0, 0, 0};
    int j = vpt ? np[0] : -1;
    bf16x8 a[KS], an[KS];
#pragma unroll
    for (int ks = 0; ks < KS; ++ks)
      a[ks] = (j >= 0) ? *(const bf16x8*)(feats + (size_t)j * K + ks * 32 + kr * 8) : zf;
    for (int o = 0; o < NOFF; ++o) {
      int jn = (o + 1 < NOFF && vpt) ? np[o + 1] : -1;
#pragma unroll
      for (int ks = 0; ks < KS; ++ks)
        an[ks] = (jn >= 0) ? *(const bf16x8*)(feats + (size_t)jn * K + ks * 32 + kr * 8) : zf;
      const u16* bw = wfrag + (size_t)o * (KS * 2048) + lane * 8;
#pragma unroll
      for (int ks = 0; ks < KS; ++ks) {
        const u16* bwk = bw + ks * 2048;
        acc0 = __builtin_amdgcn_mfma_f32_16x16x32_bf16(a[ks], *(const bf16x8*)(bwk), acc0, 0, 0, 0);
        acc1 = __builtin_amdgcn_mfma_f32_16x16x32_bf16(a[ks], *(const bf16x8*)(bwk + 512), acc1, 0, 0, 0);
        acc2 = __builtin_amdgcn_mfma_f32_16x16x32_bf16(a[ks], *(const bf16x8*)(bwk + 1024), acc2, 0, 0, 0);
        acc3 = __builtin_amdgcn_mfma_f32_16x16x32_bf16(a[ks], *(const bf16x8*)(bwk + 1536), acc3, 0, 0, 0);
      }
#pragma unroll
      for (int ks = 0; ks < KS; ++ks) a[ks] = an[ks];
    }
    float s0 = 0.f, s1 = 0.f, s2 = 0.f, s3 = 0.f;
    float q0 = 0.f, q1 = 0.f, q2 = 0.f, q3 = 0.f;
#pragma unroll
    for (int r = 0; r < 4; ++r) {
      int po = base + kr * 4 + r;
      if (po < cnt) {
        float* op = out + (size_t)po * 64 + am;
        op[0] = acc0[r]; op[16] = acc1[r]; op[32] = acc2[r]; op[48] = acc3[r];
        s0 += acc0[r]; q0 += acc0[r] * acc0[r];
        s1 += acc1[r]; q1 += acc1[r] * acc1[r];
        s2 += acc2[r]; q2 += acc2[r] * acc2[r];
        s3 += acc3[r]; q3 += acc3[r] * acc3[r];
      }
    }
    atomicAdd(&lsum[am], s0); atomicAdd(&lss[am], q0);
    atomicAdd(&lsum[am + 16], s1); atomicAdd(&lss[am + 16], q1);
    atomicAdd(&lsum[am + 32], s2); atomicAdd(&lss[am + 32], q2);
    atomicAdd(&lsum[am + 48], s3); atomicAdd(&lss[am + 48], q3);
  }
  __syncthreads();
  if (t < 64 && (lsum[t] != 0.f || lss[t] != 0.f)) {
    atomicAdd(&stats[t], lsum[t]);
    atomicAdd(&stats[64 + t], lss[t]);
  }
}

// ---- BN normalize + ReLU -> bf16 ----
__global__ void k_norm(const float* __restrict__ x, const int* __restrict__ cntp,
                       const float* __restrict__ stats, const void* __restrict__ gamma,
                       const void* __restrict__ beta, u16* __restrict__ y,
                       const int* __restrict__ flag) {
  int cnt = *cntp;
  int t = blockIdx.x * blockDim.x + threadIdx.x;
  int i = t >> 6, c = t & 63;
  if (i >= cnt) return;
  int bf = *flag;
  float g = bf ? bf2f(((const u16*)gamma)[c]) : ((const float*)gamma)[c];
  float bb = bf ? bf2f(((const u16*)beta)[c]) : ((const float*)beta)[c];
  float cf = (float)(cnt > 0 ? cnt : 1);
  float mean = stats[c] / cf;
  float var = stats[64 + c] / cf - mean * mean;
  float inv = rsqrtf(var + 1e-3f);
  float v = (x[(size_t)i * 64 + c] - mean) * inv * g + bb;
  y[(size_t)i * 64 + c] = f2bf(fmaxf(v, 0.f));
}

__global__ void k_zero_out(uint4* __restrict__ p, int n_fp32_chunks, const int* __restrict__ flag) {
  int i = blockIdx.x * blockDim.x + threadIdx.x;
  int n = (*flag) ? (n_fp32_chunks >> 1) : n_fp32_chunks;
  if (i < n) {
    uint4 z;
    z.x = 0; z.y = 0; z.z = 0; z.w = 0;
    p[i] = z;
  }
}

// ---- final BN + ReLU fused with dense scatter ----
__global__ void k_norm_scatter(const float* __restrict__ x, const int* __restrict__ cntp,
                               const float* __restrict__ stats, const void* __restrict__ gamma,
                               const void* __restrict__ beta, const int* __restrict__ coords,
                               void* __restrict__ out, const int* __restrict__ flag) {
  int t = blockIdx.x * blockDim.x + threadIdx.x;
  int i = t >> 6, c = t & 63;
  int cnt = *cntp;
  if (i >= cnt) return;
  int bf = *flag;
  float g = bf ? bf2f(((const u16*)gamma)[c]) : ((const float*)gamma)[c];
  float bb = bf ? bf2f(((const u16*)beta)[c]) : ((const float*)beta)[c];
  float cf = (float)(cnt > 0 ? cnt : 1);
  float mean = stats[c] / cf;
  float var = stats[64 + c] / cf - mean * mean;
  float inv = rsqrtf(var + 1e-3f);
  float v = fmaxf((x[(size_t)i * 64 + c] - mean) * inv * g + bb, 0.f);
  int b = coords[i * 4], oz = coords[i * 4 + 1], yy = coords[i * 4 + 2], xx = coords[i * 4 + 3];
  size_t oidx = (((size_t)(b * 64 + c) * D2_ + oz) * H_ + yy) * W_ + xx;
  if (bf) ((u16*)out)[oidx] = f2bf(v);
  else ((float*)out)[oidx] = v;
}

extern "C" void kernel_launch(void* const* d_in, const int* in_sizes, int n_in,
                              void* d_out, int out_size, void* d_ws, size_t ws_size,
                              hipStream_t stream) {
  const int N = in_sizes[0] / 128;
  const int cap1 = 2 * N + 8;
  const int cap2 = 4 * N + 8;

  char* ws = (char*)d_ws;
  size_t off = 0;
  auto alloc = [&](size_t bytes) -> void* {
    size_t o = off;
    off = (off + bytes + 255) & ~(size_t)255;
    return (void*)(ws + o);
  };

  int* ctrl = (int*)alloc(16);  // [0]=cnt0(=N) [1]=cnt1 [2]=cnt2
  int* flag = (int*)alloc(16);  // dtype flag: 1=bf16, 0=fp32
  float* stats = (float*)alloc(768 * 4);
  size_t fill_beg = off;
  int* idx0 = (int*)alloc((size_t)B_ * D0_ * HW_ * 4);
  int* idx1 = (int*)alloc((size_t)B_ * D1_ * HW_ * 4);   // claim map level 1
  int* claim2 = (int*)alloc((size_t)B_ * D2_ * HW_ * 4); // claim map level 2
  size_t fill_end = off;
  int* nbr0 = (int*)alloc((size_t)N * 27 * 4);
  int* nbr1 = (int*)alloc((size_t)cap1 * 27 * 4);
  int* nbrz1 = (int*)alloc((size_t)cap1 * 3 * 4);
  int* nbrz2 = (int*)alloc((size_t)cap2 * 3 * 4);
  int* coords1 = (int*)alloc((size_t)cap1 * 4 * 4);
  int* coords2 = (int*)alloc((size_t)cap2 * 4 * 4);
  float* xbuf = (float*)alloc((size_t)cap2 * 64 * 4);
  u16* fb = (u16*)alloc((size_t)N * 128 * 2);
  u16* y0 = (u16*)alloc((size_t)N * 64 * 2);
  u16* y1 = (u16*)alloc((size_t)cap1 * 64 * 2);
  u16* y2 = (u16*)alloc((size_t)cap1 * 64 * 2);
  u16* y3 = (u16*)alloc((size_t)cap1 * 64 * 2);
  u16* wf0 = (u16*)alloc((size_t)27 * 4 * 2048 * 2);
  u16* wf1a = (u16*)alloc((size_t)27 * 2 * 2048 * 2);
  u16* wf1b = (u16*)alloc((size_t)27 * 2 * 2048 * 2);
  u16* wfz1 = (u16*)alloc((size_t)3 * 2 * 2048 * 2);
  u16* wfz2 = (u16*)alloc((size_t)3 * 2 * 2048 * 2);

  const int* coors = (const int*)d_in[1];
  auto gr = [](long n) { return dim3((unsigned)((n + 255) / 256)); };

  k_detect<<<1, 256, 0, stream>>>((const u16*)d_in[0], flag);
  k_init<<<1, 256, 0, stream>>>(ctrl, stats, N);

  // one fused -1 fill over idx0 + idx1 + claim2 (contiguous in ws)
  long nfill16 = (long)((fill_end - fill_beg) / 16);
  k_fillm1<<<gr(nfill16), 256, 0, stream>>>((uint4*)(ws + fill_beg), (int)nfill16);
  k_scatter_idx<<<gr(N), 256, 0, stream>>>(coors, N, idx0);

  k_cvt<<<gr((long)N * 128), 256, 0, stream>>>(d_in[0], fb, N * 128, flag);
  k_repack<<<gr(27 * 4 * 2048), 256, 0, stream>>>(d_in[3], wf0, 128, 27, flag);
  k_repack<<<gr(27 * 2 * 2048), 256, 0, stream>>>(d_in[9], wf1a, 64, 27, flag);
  k_repack<<<gr(27 * 2 * 2048), 256, 0, stream>>>(d_in[12], wf1b, 64, 27, flag);
  k_repack<<<gr(3 * 2 * 2048), 256, 0, stream>>>(d_in[6], wfz1, 64, 3, flag);
  k_repack<<<gr(3 * 2 * 2048), 256, 0, stream>>>(d_in[15], wfz2, 64, 3, flag);

  int n16 = out_size / 4;
  k_zero_out<<<gr(n16), 256, 0, stream>>>((uint4*)d_out, n16, flag);

  // ---- level 0: subm conv (128 -> 64) + fused stats, then BN/ReLU ----
  k_nbr27<<<gr((long)N * 27), 256, 0, stream>>>(coors, ctrl + 0, idx0, D0_, nbr0, N);
  k_conv<128, 27><<<dim3((N + 63) / 64), 256, 0, stream>>>(fb, nbr0, wf0, xbuf, ctrl + 0, stats + 0);
  k_norm<<<gr((long)N * 64), 256, 0, stream>>>(xbuf, ctrl + 0, stats + 0, d_in[4], d_in[5], y0, flag);

  // ---- downsample z: D0 -> D1 (point-driven claim) ----
  k_claim<<<gr(N), 256, 0, stream>>>(coors, ctrl + 0, idx0, D0_, D1_, idx1, coords1, nbrz1, ctrl + 1);
  k_conv<64, 3><<<dim3((cap1 + 63) / 64), 256, 0, stream>>>(y0, nbrz1, wfz1, xbuf, ctrl + 1, stats + 128);
  k_norm<<<gr((long)cap1 * 64), 256, 0, stream>>>(xbuf, ctrl + 1, stats + 128, d_in[7], d_in[8], y1, flag);

  // ---- level 1: subm conv a ----
  k_nbr27<<<gr((long)cap1 * 27), 256, 0, stream>>>(coords1, ctrl + 1, idx1, D1_, nbr1, cap1);
  k_conv<64, 27><<<dim3((cap1 + 63) / 64), 256, 0, stream>>>(y1, nbr1, wf1a, xbuf, ctrl + 1, stats + 256);
  k_norm<<<gr((long)cap1 * 64), 256, 0, stream>>>(xbuf, ctrl + 1, stats + 256, d_in[10], d_in[11], y2, flag);

  // ---- level 1: subm conv b ----
  k_conv<64, 27><<<dim3((cap1 + 63) / 64), 256, 0, stream>>>(y2, nbr1, wf1b, xbuf, ctrl + 1, stats + 384);
  k_norm<<<gr((long)cap1 * 64), 256, 0, stream>>>(xbuf, ctrl + 1, stats + 384, d_in[13], d_in[14], y3, flag);

  // ---- downsample z: D1 -> D2 (point-driven claim) ----
  k_claim<<<gr(cap1), 256, 0, stream>>>(coords1, ctrl + 1, idx1, D1_, D2_, claim2, coords2, nbrz2, ctrl + 2);
  k_conv<64, 3><<<dim3((cap2 + 63) / 64), 256, 0, stream>>>(y3, nbrz2, wfz2, xbuf, ctrl + 2, stats + 512);

  // ---- final BN + ReLU + dense scatter ----
  k_norm_scatter<<<gr((long)cap2 * 64), 256, 0, stream>>>(xbuf, ctrl + 2, stats + 512,
                                                          d_in[16], d_in[17], coords2,
                                                          d_out, flag);
}

// Round 5
// 499.116 us; speedup vs baseline: 1.7696x; 1.0839x over previous
//
#include <hip/hip_runtime.h>

typedef unsigned short u16;
typedef unsigned int u32;
typedef unsigned long long u64;
typedef __attribute__((ext_vector_type(8))) short bf16x8;
typedef __attribute__((ext_vector_type(4))) float f32x4;

#define H_ 200
#define W_ 176
#define HW_ (200 * 176)
#define D0_ 41
#define D1_ 20
#define D2_ 9
#define B_ 2

__device__ __forceinline__ u16 f2bf(float f) {
  union { float f; u32 u; } c; c.f = f;
  u32 u = c.u;
  u32 r = (u + 0x7fffu + ((u >> 16) & 1u)) >> 16;
  return (u16)r;
}

// ---- setup: -1 fill of idx maps + ctrl + stats, one kernel ----
__global__ void k_setup(int* __restrict__ ctrl, float* __restrict__ stats,
                        uint4* __restrict__ fillp, int nfill16, int N) {
  int t = blockIdx.x * 256 + threadIdx.x;
  if (t < nfill16) {
    uint4 v;
    v.x = 0xFFFFFFFFu; v.y = 0xFFFFFFFFu; v.z = 0xFFFFFFFFu; v.w = 0xFFFFFFFFu;
    fillp[t] = v;
    return;
  }
  int u = t - nfill16;
  if (u < 3) ctrl[u] = (u == 0) ? N : 0;
  else if (u < 3 + 768) stats[u - 3] = 0.f;
}

// ---- weight repack helper: (NOFF,K,64) fp32 -> bf16 fragment order [o][ks][nt][lane][8] ----
__device__ __forceinline__ void repack1(const float* __restrict__ w, u16* __restrict__ frag,
                                        int K, int t) {
  int j = t & 7;
  int lane = (t >> 3) & 63;
  int nt = (t >> 9) & 3;
  int rest = t >> 11;
  int KS = K / 32;
  int ks = rest % KS;
  int o = rest / KS;
  int k = ks * 32 + (lane >> 4) * 8 + j;
  int n = nt * 16 + (lane & 15);
  frag[t] = f2bf(w[((size_t)o * K + k) * 64 + n]);
}

// ---- prep: feats fp32->bf16, 5 weight repacks, idx0 scatter — one kernel ----
// segment sizes are NOFF*KS*2048: w0=27*4*2048=221184, w1=27*2*2048=110592,
// wz=3*2*2048=12288  (round-4 bug: wz segments were 6144 -> half-poisoned frags)
__global__ void k_prep(const float* __restrict__ feats, const float* __restrict__ w0s,
                       const float* __restrict__ w1as, const float* __restrict__ w1bs,
                       const float* __restrict__ wz1s, const float* __restrict__ wz2s,
                       const int* __restrict__ coors,
                       u16* __restrict__ fb, u16* __restrict__ wf0, u16* __restrict__ wf1a,
                       u16* __restrict__ wf1b, u16* __restrict__ wfz1, u16* __restrict__ wfz2,
                       int* __restrict__ idx0, int N) {
  int t = blockIdx.x * 256 + threadIdx.x;
  int NC = N * 128;
  if (t < NC) { fb[t] = f2bf(feats[t]); return; }
  t -= NC;
  if (t < 221184) { repack1(w0s, wf0, 128, t); return; }
  t -= 221184;
  if (t < 110592) { repack1(w1as, wf1a, 64, t); return; }
  t -= 110592;
  if (t < 110592) { repack1(w1bs, wf1b, 64, t); return; }
  t -= 110592;
  if (t < 12288) { repack1(wz1s, wfz1, 64, t); return; }
  t -= 12288;
  if (t < 12288) { repack1(wz2s, wfz2, 64, t); return; }
  t -= 12288;
  if (t < N) {
    int b = coors[t * 4], z = coors[t * 4 + 1], y = coors[t * 4 + 2], x = coors[t * 4 + 3];
    idx0[((size_t)(b * D0_ + z) * H_ + y) * W_ + x] = t;
  }
}

// ---- subm 3^3 conv, inline neighbor gen (no nbr table), fused BN stats ----
template <int K>
__global__ __launch_bounds__(256) void k_conv27(const u16* __restrict__ feats,
                                                const int* __restrict__ coords,
                                                const int* __restrict__ idxmap, int D,
                                                const u16* __restrict__ wfrag,
                                                float* __restrict__ out,
                                                const int* __restrict__ cntp,
                                                float* __restrict__ stats) {
  constexpr int KS = K / 32;
  __shared__ float lsum[64], lss[64];
  int cnt = *cntp;
  int t = threadIdx.x;
  if (t < 64) { lsum[t] = 0.f; lss[t] = 0.f; }
  __syncthreads();
  int lane = t & 63;
  int base = (blockIdx.x * 4 + (t >> 6)) * 16;
  bool active = base < cnt;
  int am = lane & 15;
  int kr = lane >> 4;
  int pt = base + am;
  bool vpt = active && (pt < cnt);
  f32x4 acc0 = {0.f, 0.f, 0.f, 0.f};
  f32x4 acc1 = acc0, acc2 = acc0, acc3 = acc0;
  if (active) {
    int b = 0, z = 0, y = 0, x = 0;
    if (vpt) {
      int4 cc = *(const int4*)(coords + (size_t)pt * 4);
      b = cc.x; z = cc.y; y = cc.z; x = cc.w;
    }
    bool gat = vpt && (kr == 0);
    auto gatherJ = [&](int o) -> int {
      if (!gat) return -1;
      int nz = z + o / 9 - 1;
      int ny = y + (o / 3) % 3 - 1;
      int nx = x + o % 3 - 1;
      if ((u32)nz >= (u32)D || (u32)ny >= (u32)H_ || (u32)nx >= (u32)W_) return -1;
      return idxmap[((size_t)(b * D + nz) * H_ + ny) * W_ + nx];
    };
    bf16x8 zf = {0, 0, 0, 0, 0, 0, 0, 0};
    bf16x8 a[KS], an[KS];
    int jg = gatherJ(0);
    int j = __shfl(jg, am);
#pragma unroll
    for (int ks = 0; ks < KS; ++ks)
      a[ks] = (j >= 0) ? *(const bf16x8*)(feats + (size_t)j * K + ks * 32 + kr * 8) : zf;
    jg = gatherJ(1);
    for (int o = 0; o < 27; ++o) {
      int jn = (o + 1 < 27) ? __shfl(jg, am) : -1;
      if (o + 2 < 27) jg = gatherJ(o + 2);
#pragma unroll
      for (int ks = 0; ks < KS; ++ks)
        an[ks] = (jn >= 0) ? *(const bf16x8*)(feats + (size_t)jn * K + ks * 32 + kr * 8) : zf;
      const u16* bw = wfrag + (size_t)o * (KS * 2048) + lane * 8;
#pragma unroll
      for (int ks = 0; ks < KS; ++ks) {
        const u16* bwk = bw + ks * 2048;
        acc0 = __builtin_amdgcn_mfma_f32_16x16x32_bf16(a[ks], *(const bf16x8*)(bwk), acc0, 0, 0, 0);
        acc1 = __builtin_amdgcn_mfma_f32_16x16x32_bf16(a[ks], *(const bf16x8*)(bwk + 512), acc1, 0, 0, 0);
        acc2 = __builtin_amdgcn_mfma_f32_16x16x32_bf16(a[ks], *(const bf16x8*)(bwk + 1024), acc2, 0, 0, 0);
        acc3 = __builtin_amdgcn_mfma_f32_16x16x32_bf16(a[ks], *(const bf16x8*)(bwk + 1536), acc3, 0, 0, 0);
      }
#pragma unroll
      for (int ks = 0; ks < KS; ++ks) a[ks] = an[ks];
    }
    float s0 = 0.f, s1 = 0.f, s2 = 0.f, s3 = 0.f;
    float q0 = 0.f, q1 = 0.f, q2 = 0.f, q3 = 0.f;
#pragma unroll
    for (int r = 0; r < 4; ++r) {
      int po = base + kr * 4 + r;
      if (po < cnt) {
        float* op = out + (size_t)po * 64 + am;
        op[0] = acc0[r]; op[16] = acc1[r]; op[32] = acc2[r]; op[48] = acc3[r];
        s0 += acc0[r]; q0 += acc0[r] * acc0[r];
        s1 += acc1[r]; q1 += acc1[r] * acc1[r];
        s2 += acc2[r]; q2 += acc2[r] * acc2[r];
        s3 += acc3[r]; q3 += acc3[r] * acc3[r];
      }
    }
    atomicAdd(&lsum[am], s0); atomicAdd(&lss[am], q0);
    atomicAdd(&lsum[am + 16], s1); atomicAdd(&lss[am + 16], q1);
    atomicAdd(&lsum[am + 32], s2); atomicAdd(&lss[am + 32], q2);
    atomicAdd(&lsum[am + 48], s3); atomicAdd(&lss[am + 48], q3);
  }
  __syncthreads();
  if (t < 64 && (lsum[t] != 0.f || lss[t] != 0.f)) {
    atomicAdd(&stats[t], lsum[t]);
    atomicAdd(&stats[64 + t], lss[t]);
  }
}

// ---- strided z conv (3-tap, K=64) via nbrz table, fused BN stats ----
__global__ __launch_bounds__(256) void k_convz(const u16* __restrict__ feats,
                                               const int* __restrict__ nbr,
                                               const u16* __restrict__ wfrag,
                                               float* __restrict__ out,
                                               const int* __restrict__ cntp,
                                               float* __restrict__ stats) {
  constexpr int KS = 2;
  __shared__ float lsum[64], lss[64];
  int cnt = *cntp;
  int t = threadIdx.x;
  if (t < 64) { lsum[t] = 0.f; lss[t] = 0.f; }
  __syncthreads();
  int lane = t & 63;
  int base = (blockIdx.x * 4 + (t >> 6)) * 16;
  bool active = base < cnt;
  int am = lane & 15;
  int kr = lane >> 4;
  int pt = base + am;
  bool vpt = active && (pt < cnt);
  f32x4 acc0 = {0.f, 0.f, 0.f, 0.f};
  f32x4 acc1 = acc0, acc2 = acc0, acc3 = acc0;
  if (active) {
    const int* np = nbr + (size_t)pt * 3;
    bf16x8 zf = {0, 0, 0, 0, 0, 0, 0, 0};
    int j = vpt ? np[0] : -1;
    bf16x8 a[KS], an[KS];
#pragma unroll
    for (int ks = 0; ks < KS; ++ks)
      a[ks] = (j >= 0) ? *(const bf16x8*)(feats + (size_t)j * 64 + ks * 32 + kr * 8) : zf;
    for (int o = 0; o < 3; ++o) {
      int jn = (o + 1 < 3 && vpt) ? np[o + 1] : -1;
#pragma unroll
      for (int ks = 0; ks < KS; ++ks)
        an[ks] = (jn >= 0) ? *(const bf16x8*)(feats + (size_t)jn * 64 + ks * 32 + kr * 8) : zf;
      const u16* bw = wfrag + (size_t)o * (KS * 2048) + lane * 8;
#pragma unroll
      for (int ks = 0; ks < KS; ++ks) {
        const u16* bwk = bw + ks * 2048;
        acc0 = __builtin_amdgcn_mfma_f32_16x16x32_bf16(a[ks], *(const bf16x8*)(bwk), acc0, 0, 0, 0);
        acc1 = __builtin_amdgcn_mfma_f32_16x16x32_bf16(a[ks], *(const bf16x8*)(bwk + 512), acc1, 0, 0, 0);
        acc2 = __builtin_amdgcn_mfma_f32_16x16x32_bf16(a[ks], *(const bf16x8*)(bwk + 1024), acc2, 0, 0, 0);
        acc3 = __builtin_amdgcn_mfma_f32_16x16x32_bf16(a[ks], *(const bf16x8*)(bwk + 1536), acc3, 0, 0, 0);
      }
#pragma unroll
      for (int ks = 0; ks < KS; ++ks) a[ks] = an[ks];
    }
    float s0 = 0.f, s1 = 0.f, s2 = 0.f, s3 = 0.f;
    float q0 = 0.f, q1 = 0.f, q2 = 0.f, q3 = 0.f;
#pragma unroll
    for (int r = 0; r < 4; ++r) {
      int po = base + kr * 4 + r;
      if (po < cnt) {
        float* op = out + (size_t)po * 64 + am;
        op[0] = acc0[r]; op[16] = acc1[r]; op[32] = acc2[r]; op[48] = acc3[r];
        s0 += acc0[r]; q0 += acc0[r] * acc0[r];
        s1 += acc1[r]; q1 += acc1[r] * acc1[r];
        s2 += acc2[r]; q2 += acc2[r] * acc2[r];
        s3 += acc3[r]; q3 += acc3[r] * acc3[r];
      }
    }
    atomicAdd(&lsum[am], s0); atomicAdd(&lss[am], q0);
    atomicAdd(&lsum[am + 16], s1); atomicAdd(&lss[am + 16], q1);
    atomicAdd(&lsum[am + 32], s2); atomicAdd(&lss[am + 32], q2);
    atomicAdd(&lsum[am + 48], s3); atomicAdd(&lss[am + 48], q3);
  }
  __syncthreads();
  if (t < 64 && (lsum[t] != 0.f || lss[t] != 0.f)) {
    atomicAdd(&stats[t], lsum[t]);
    atomicAdd(&stats[64 + t], lss[t]);
  }
}

// ---- BN normalize + ReLU -> bf16 ----
__global__ void k_norm(const float* __restrict__ x, const int* __restrict__ cntp,
                       const float* __restrict__ stats, const float* __restrict__ gamma,
                       const float* __restrict__ beta, u16* __restrict__ y) {
  int cnt = *cntp;
  int t = blockIdx.x * 256 + threadIdx.x;
  int i = t >> 6, c = t & 63;
  if (i >= cnt) return;
  float cf = (float)(cnt > 0 ? cnt : 1);
  float mean = stats[c] / cf;
  float var = stats[64 + c] / cf - mean * mean;
  float inv = rsqrtf(var + 1e-3f);
  float v = (x[(size_t)i * 64 + c] - mean) * inv * gamma[c] + beta[c];
  y[(size_t)i * 64 + c] = f2bf(fmaxf(v, 0.f));
}

// ---- fused: BN norm of level L + claim/downsample L -> L+1 ----
__global__ void k_norm_claim(const float* __restrict__ x, const int* __restrict__ cntp,
                             const float* __restrict__ stats, const float* __restrict__ gamma,
                             const float* __restrict__ beta, u16* __restrict__ y, int normCap,
                             const int* __restrict__ coordsIn, const int* __restrict__ idxin,
                             int Din, int Dout, int* __restrict__ claim,
                             int* __restrict__ coords_out, int* __restrict__ nbrz,
                             int* __restrict__ outcnt, int claimCap) {
  int t = blockIdx.x * 256 + threadIdx.x;
  int cnt = *cntp;
  if (t < normCap) {
    int i = t >> 6, c = t & 63;
    if (i >= cnt) return;
    float cf = (float)(cnt > 0 ? cnt : 1);
    float mean = stats[c] / cf;
    float var = stats[64 + c] / cf - mean * mean;
    float inv = rsqrtf(var + 1e-3f);
    float v = (x[(size_t)i * 64 + c] - mean) * inv * gamma[c] + beta[c];
    y[(size_t)i * 64 + c] = f2bf(fmaxf(v, 0.f));
    return;
  }
  // claim region: waves are 64-aligned (normCap % 64 == 0)
  int i = t - normCap;
  bool w0 = false, w1 = false;
  int pos0 = 0, pos1 = 0, oz0 = -1, oz1 = -1;
  int b = 0, z = 0, yy = 0, xx = 0;
  if (i < claimCap && i < cnt) {
    int4 cc = *(const int4*)(coordsIn + (size_t)i * 4);
    b = cc.x; z = cc.y; yy = cc.z; xx = cc.w;
    if (z & 1) {
      int oz = (z - 1) >> 1;
      if (oz < Dout) oz0 = oz;
    } else {
      int oz = z >> 1;
      if (oz < Dout) oz0 = oz;
      if (z >= 2) oz1 = oz - 1;
    }
    if (oz0 >= 0) {
      pos0 = ((b * Dout + oz0) * H_ + yy) * W_ + xx;
      w0 = (atomicCAS(&claim[pos0], -1, -2) == -1);
    }
    if (oz1 >= 0) {
      pos1 = ((b * Dout + oz1) * H_ + yy) * W_ + xx;
      w1 = (atomicCAS(&claim[pos1], -1, -2) == -1);
    }
  }
  u64 m0 = __ballot(w0), m1 = __ballot(w1);
  int c0 = __popcll(m0), c1 = __popcll(m1);
  int lane = threadIdx.x & 63;
  u64 lt = (lane == 63) ? 0x7FFFFFFFFFFFFFFFull : ((1ull << lane) - 1ull);
  int bse2 = 0;
  if (lane == 0 && (c0 + c1) > 0) bse2 = atomicAdd(outcnt, c0 + c1);
  bse2 = __shfl(bse2, 0);
  if (w0) {
    int id = bse2 + __popcll(m0 & lt);
    claim[pos0] = id;
    coords_out[id * 4 + 0] = b; coords_out[id * 4 + 1] = oz0;
    coords_out[id * 4 + 2] = yy; coords_out[id * 4 + 3] = xx;
    size_t bse = ((size_t)(b * Din + 2 * oz0) * H_ + yy) * W_ + xx;
    nbrz[id * 3 + 0] = idxin[bse];
    nbrz[id * 3 + 1] = idxin[bse + HW_];
    nbrz[id * 3 + 2] = idxin[bse + 2 * (size_t)HW_];
  }
  if (w1) {
    int id = bse2 + c0 + __popcll(m1 & lt);
    claim[pos1] = id;
    coords_out[id * 4 + 0] = b; coords_out[id * 4 + 1] = oz1;
    coords_out[id * 4 + 2] = yy; coords_out[id * 4 + 3] = xx;
    size_t bse = ((size_t)(b * Din + 2 * oz1) * H_ + yy) * W_ + xx;
    nbrz[id * 3 + 0] = idxin[bse];
    nbrz[id * 3 + 1] = idxin[bse + HW_];
    nbrz[id * 3 + 2] = idxin[bse + 2 * (size_t)HW_];
  }
}

// ---- dense output: BN+ReLU of level-2, full dense write (zero where empty) ----
__global__ void k_output(const float* __restrict__ x, const int* __restrict__ cntp,
                         const float* __restrict__ stats, const float* __restrict__ gamma,
                         const float* __restrict__ beta, const int* __restrict__ claim2,
                         float* __restrict__ out) {
  const int XQ = W_ / 4;  // 44
  int t = blockIdx.x * 256 + threadIdx.x;
  int total = B_ * 64 * D2_ * H_ * XQ;
  if (t >= total) return;
  int xq = t % XQ;
  int row = t / XQ;
  int y = row % H_;
  int r2 = row / H_;
  int oz = r2 % D2_;
  r2 /= D2_;
  int c = r2 & 63;
  int b = r2 >> 6;
  int cnt = *cntp;
  float cf = (float)(cnt > 0 ? cnt : 1);
  float mean = stats[c] / cf;
  float var = stats[64 + c] / cf - mean * mean;
  float inv = rsqrtf(var + 1e-3f);
  float g = gamma[c] * inv;
  float bb = beta[c] - mean * g;
  int pos = ((b * D2_ + oz) * H_ + y) * W_ + xq * 4;
  int4 ids = *(const int4*)(claim2 + pos);
  float4 v;
  v.x = (ids.x >= 0) ? fmaxf(x[(size_t)ids.x * 64 + c] * g + bb, 0.f) : 0.f;
  v.y = (ids.y >= 0) ? fmaxf(x[(size_t)ids.y * 64 + c] * g + bb, 0.f) : 0.f;
  v.z = (ids.z >= 0) ? fmaxf(x[(size_t)ids.z * 64 + c] * g + bb, 0.f) : 0.f;
  v.w = (ids.w >= 0) ? fmaxf(x[(size_t)ids.w * 64 + c] * g + bb, 0.f) : 0.f;
  *(float4*)(out + (size_t)row * W_ + xq * 4) = v;
}

extern "C" void kernel_launch(void* const* d_in, const int* in_sizes, int n_in,
                              void* d_out, int out_size, void* d_ws, size_t ws_size,
                              hipStream_t stream) {
  const int N = in_sizes[0] / 128;
  const int cap1 = 2 * N + 8;
  const int cap2 = 4 * N + 8;

  char* ws = (char*)d_ws;
  size_t off = 0;
  auto alloc = [&](size_t bytes) -> void* {
    size_t o = off;
    off = (off + bytes + 255) & ~(size_t)255;
    return (void*)(ws + o);
  };

  int* ctrl = (int*)alloc(16);  // [0]=cnt0(=N) [1]=cnt1 [2]=cnt2
  float* stats = (float*)alloc(768 * 4);
  size_t fill_beg = off;
  int* idx0 = (int*)alloc((size_t)B_ * D0_ * HW_ * 4);
  int* idx1 = (int*)alloc((size_t)B_ * D1_ * HW_ * 4);   // claim map level 1
  int* claim2 = (int*)alloc((size_t)B_ * D2_ * HW_ * 4); // claim map level 2
  size_t fill_end = off;
  int* nbrz1 = (int*)alloc((size_t)cap1 * 3 * 4);
  int* nbrz2 = (int*)alloc((size_t)cap2 * 3 * 4);
  int* coords1 = (int*)alloc((size_t)cap1 * 4 * 4);
  int* coords2 = (int*)alloc((size_t)cap2 * 4 * 4);
  float* xbuf = (float*)alloc((size_t)cap2 * 64 * 4);
  u16* fb = (u16*)alloc((size_t)N * 128 * 2);
  u16* y0 = (u16*)alloc((size_t)N * 64 * 2);
  u16* y1 = (u16*)alloc((size_t)cap1 * 64 * 2);
  u16* y2 = (u16*)alloc((size_t)cap1 * 64 * 2);
  u16* y3 = (u16*)alloc((size_t)cap1 * 64 * 2);
  u16* wf0 = (u16*)alloc((size_t)27 * 4 * 2048 * 2);
  u16* wf1a = (u16*)alloc((size_t)27 * 2 * 2048 * 2);
  u16* wf1b = (u16*)alloc((size_t)27 * 2 * 2048 * 2);
  u16* wfz1 = (u16*)alloc((size_t)3 * 2 * 2048 * 2);
  u16* wfz2 = (u16*)alloc((size_t)3 * 2 * 2048 * 2);

  const int* coors = (const int*)d_in[1];
  auto gr = [](long n) { return dim3((unsigned)((n + 255) / 256)); };

  // 1: setup (fills + counters + stats)
  int nfill16 = (int)((fill_end - fill_beg) / 16);
  k_setup<<<gr((long)nfill16 + 771), 256, 0, stream>>>(ctrl, stats,
                                                       (uint4*)(ws + fill_beg), nfill16, N);

  // 2: prep (cvt + 5 repacks + idx0 scatter)
  long prepTotal = (long)N * 128 + 221184 + 110592 + 110592 + 12288 + 12288 + N;
  k_prep<<<gr(prepTotal), 256, 0, stream>>>((const float*)d_in[0], (const float*)d_in[3],
                                            (const float*)d_in[9], (const float*)d_in[12],
                                            (const float*)d_in[6], (const float*)d_in[15],
                                            coors, fb, wf0, wf1a, wf1b, wfz1, wfz2, idx0, N);

  // 3: level-0 subm conv (128->64), inline neighbors, fused stats
  k_conv27<128><<<dim3((N + 63) / 64), 256, 0, stream>>>(fb, coors, idx0, D0_, wf0, xbuf,
                                                         ctrl + 0, stats + 0);
  // 4: norm y0 + claim level1
  k_norm_claim<<<gr((long)N * 64 + N), 256, 0, stream>>>(
      xbuf, ctrl + 0, stats + 0, (const float*)d_in[4], (const float*)d_in[5], y0, N * 64,
      coors, idx0, D0_, D1_, idx1, coords1, nbrz1, ctrl + 1, N);

  // 5: z-conv 1 + stats
  k_convz<<<dim3((cap1 + 63) / 64), 256, 0, stream>>>(y0, nbrz1, wfz1, xbuf, ctrl + 1, stats + 128);
  // 6: norm y1
  k_norm<<<gr((long)cap1 * 64), 256, 0, stream>>>(xbuf, ctrl + 1, stats + 128,
                                                  (const float*)d_in[7], (const float*)d_in[8], y1);

  // 7: level-1 subm conv a
  k_conv27<64><<<dim3((cap1 + 63) / 64), 256, 0, stream>>>(y1, coords1, idx1, D1_, wf1a, xbuf,
                                                           ctrl + 1, stats + 256);
  // 8: norm y2
  k_norm<<<gr((long)cap1 * 64), 256, 0, stream>>>(xbuf, ctrl + 1, stats + 256,
                                                  (const float*)d_in[10], (const float*)d_in[11], y2);

  // 9: level-1 subm conv b
  k_conv27<64><<<dim3((cap1 + 63) / 64), 256, 0, stream>>>(y2, coords1, idx1, D1_, wf1b, xbuf,
                                                           ctrl + 1, stats + 384);
  // 10: norm y3 + claim level2
  k_norm_claim<<<gr((long)cap1 * 64 + cap1), 256, 0, stream>>>(
      xbuf, ctrl + 1, stats + 384, (const float*)d_in[13], (const float*)d_in[14], y3, cap1 * 64,
      coords1, idx1, D1_, D2_, claim2, coords2, nbrz2, ctrl + 2, cap1);

  // 11: z-conv 2 + stats
  k_convz<<<dim3((cap2 + 63) / 64), 256, 0, stream>>>(y3, nbrz2, wfz2, xbuf, ctrl + 2, stats + 512);

  // 12: dense output (BN + ReLU + zero-fill)
  long outThreads = (long)B_ * 64 * D2_ * H_ * (W_ / 4);
  k_output<<<gr(outThreads), 256, 0, stream>>>(xbuf, ctrl + 2, stats + 512,
                                               (const float*)d_in[16], (const float*)d_in[17],
                                               claim2, (float*)d_out);
}

// Round 6
// 457.597 us; speedup vs baseline: 1.9302x; 1.0907x over previous
//
#include <hip/hip_runtime.h>

typedef unsigned short u16;
typedef unsigned int u32;
typedef unsigned long long u64;
typedef __attribute__((ext_vector_type(8))) short bf16x8;
typedef __attribute__((ext_vector_type(4))) float f32x4;

#define H_ 200
#define W_ 176
#define HW_ (200 * 176)
#define D0_ 41
#define D1_ 20
#define D2_ 9
#define B_ 2

__device__ __forceinline__ u16 f2bf(float f) {
  union { float f; u32 u; } c; c.f = f;
  u32 u = c.u;
  u32 r = (u + 0x7fffu + ((u >> 16) & 1u)) >> 16;
  return (u16)r;
}

// ---- setup: -1 fill (idx maps) + zero fill (group masks) + ctrl + stats ----
__global__ void k_setup(int* __restrict__ ctrl, float* __restrict__ stats,
                        uint4* __restrict__ fillp, int nfill16,
                        uint4* __restrict__ zerop, int nzero16, int N) {
  int t = blockIdx.x * 256 + threadIdx.x;
  if (t < nfill16) {
    uint4 v;
    v.x = 0xFFFFFFFFu; v.y = 0xFFFFFFFFu; v.z = 0xFFFFFFFFu; v.w = 0xFFFFFFFFu;
    fillp[t] = v;
    return;
  }
  t -= nfill16;
  if (t < nzero16) {
    uint4 z;
    z.x = 0; z.y = 0; z.z = 0; z.w = 0;
    zerop[t] = z;
    return;
  }
  t -= nzero16;
  if (t < 3) ctrl[t] = (t == 0) ? N : 0;
  else if (t < 3 + 768) stats[t - 3] = 0.f;
}

// ---- weight repack helper: (NOFF,K,64) fp32 -> bf16 fragment order [o][ks][nt][lane][8] ----
__device__ __forceinline__ void repack1(const float* __restrict__ w, u16* __restrict__ frag,
                                        int K, int t) {
  int j = t & 7;
  int lane = (t >> 3) & 63;
  int nt = (t >> 9) & 3;
  int rest = t >> 11;
  int KS = K / 32;
  int ks = rest % KS;
  int o = rest / KS;
  int k = ks * 32 + (lane >> 4) * 8 + j;
  int n = nt * 16 + (lane & 15);
  frag[t] = f2bf(w[((size_t)o * K + k) * 64 + n]);
}

// ---- prep: feats fp32->bf16, 5 weight repacks, idx0 scatter ----
__global__ void k_prep(const float* __restrict__ feats, const float* __restrict__ w0s,
                       const float* __restrict__ w1as, const float* __restrict__ w1bs,
                       const float* __restrict__ wz1s, const float* __restrict__ wz2s,
                       const int* __restrict__ coors,
                       u16* __restrict__ fb, u16* __restrict__ wf0, u16* __restrict__ wf1a,
                       u16* __restrict__ wf1b, u16* __restrict__ wfz1, u16* __restrict__ wfz2,
                       int* __restrict__ idx0, int N) {
  int t = blockIdx.x * 256 + threadIdx.x;
  int NC = N * 128;
  if (t < NC) { fb[t] = f2bf(feats[t]); return; }
  t -= NC;
  if (t < 221184) { repack1(w0s, wf0, 128, t); return; }
  t -= 221184;
  if (t < 110592) { repack1(w1as, wf1a, 64, t); return; }
  t -= 110592;
  if (t < 110592) { repack1(w1bs, wf1b, 64, t); return; }
  t -= 110592;
  if (t < 12288) { repack1(wz1s, wfz1, 64, t); return; }
  t -= 12288;
  if (t < 12288) { repack1(wz2s, wfz2, 64, t); return; }
  t -= 12288;
  if (t < N) {
    int b = coors[t * 4], z = coors[t * 4 + 1], y = coors[t * 4 + 2], x = coors[t * 4 + 3];
    idx0[((size_t)(b * D0_ + z) * H_ + y) * W_ + x] = t;
  }
}

// ---- neighbor table: nbr[g][27][16] + per-group active-offset mask ----
__global__ void k_nbr(const int* __restrict__ coords, const int* __restrict__ cntp,
                      const int* __restrict__ idxmap, int D,
                      int* __restrict__ nbr, u32* __restrict__ gmask, int ngroups) {
  int t = blockIdx.x * 256 + threadIdx.x;
  int total = ngroups * 432;
  if (t >= total) return;
  int g = t / 432;
  int r = t - g * 432;
  int o = r >> 4;
  int pi = r & 15;
  int i = g * 16 + pi;
  int cnt = *cntp;
  int j = -1;
  if (i < cnt) {
    int4 cc = *(const int4*)(coords + (size_t)i * 4);
    int nz = cc.y + o / 9 - 1;
    int ny = cc.z + (o / 3) % 3 - 1;
    int nx = cc.w + o % 3 - 1;
    if ((u32)nz < (u32)D && (u32)ny < (u32)H_ && (u32)nx < (u32)W_)
      j = idxmap[((size_t)(cc.x * D + nz) * H_ + ny) * W_ + nx];
  }
  nbr[t] = j;
  // one atomicOr per 16-lane chunk (chunk == one (g,o) pair; 432 % 16 == 0)
  u64 bal = __ballot(j >= 0);
  int lane = threadIdx.x & 63;
  if ((lane & 15) == 0 && ((bal >> (lane & 48)) & 0xFFFFull))
    atomicOr(&gmask[g], 1u << o);
}

// ---- subm 3^3 conv over ACTIVE offsets only, fused BN stats ----
template <int K>
__global__ __launch_bounds__(256) void k_conv27(const u16* __restrict__ feats,
                                                const int* __restrict__ nbr,
                                                const u32* __restrict__ gmask,
                                                const u16* __restrict__ wfrag,
                                                float* __restrict__ out,
                                                const int* __restrict__ cntp,
                                                float* __restrict__ stats) {
  constexpr int KS = K / 32;
  __shared__ float lsum[64], lss[64];
  int cnt = *cntp;
  int t = threadIdx.x;
  if (t < 64) { lsum[t] = 0.f; lss[t] = 0.f; }
  __syncthreads();
  int lane = t & 63;
  int g = blockIdx.x * 4 + (t >> 6);
  int base = g * 16;
  bool active = base < cnt;
  int am = lane & 15;
  int kr = lane >> 4;
  f32x4 acc0 = {0.f, 0.f, 0.f, 0.f};
  f32x4 acc1 = acc0, acc2 = acc0, acc3 = acc0;
  if (active) {
    u32 mask = gmask[g];
    const int* nb = nbr + (size_t)g * 432 + am;
    bf16x8 zf = {0, 0, 0, 0, 0, 0, 0, 0};
    bf16x8 a[KS], an[KS];
    if (mask) {
      int o = __builtin_ctz(mask); mask &= mask - 1;
      int j = nb[o * 16];
#pragma unroll
      for (int ks = 0; ks < KS; ++ks)
        a[ks] = (j >= 0) ? *(const bf16x8*)(feats + (size_t)j * K + ks * 32 + kr * 8) : zf;
      while (true) {
        int on = -1, jn = -1;
        if (mask) { on = __builtin_ctz(mask); mask &= mask - 1; jn = nb[on * 16]; }
#pragma unroll
        for (int ks = 0; ks < KS; ++ks)
          an[ks] = (jn >= 0) ? *(const bf16x8*)(feats + (size_t)jn * K + ks * 32 + kr * 8) : zf;
        const u16* bw = wfrag + (size_t)o * (KS * 2048) + lane * 8;
#pragma unroll
        for (int ks = 0; ks < KS; ++ks) {
          const u16* bwk = bw + ks * 2048;
          acc0 = __builtin_amdgcn_mfma_f32_16x16x32_bf16(a[ks], *(const bf16x8*)(bwk), acc0, 0, 0, 0);
          acc1 = __builtin_amdgcn_mfma_f32_16x16x32_bf16(a[ks], *(const bf16x8*)(bwk + 512), acc1, 0, 0, 0);
          acc2 = __builtin_amdgcn_mfma_f32_16x16x32_bf16(a[ks], *(const bf16x8*)(bwk + 1024), acc2, 0, 0, 0);
          acc3 = __builtin_amdgcn_mfma_f32_16x16x32_bf16(a[ks], *(const bf16x8*)(bwk + 1536), acc3, 0, 0, 0);
        }
        if (on < 0) break;
        o = on;
#pragma unroll
        for (int ks = 0; ks < KS; ++ks) a[ks] = an[ks];
      }
    }
    float s0 = 0.f, s1 = 0.f, s2 = 0.f, s3 = 0.f;
    float q0 = 0.f, q1 = 0.f, q2 = 0.f, q3 = 0.f;
#pragma unroll
    for (int r = 0; r < 4; ++r) {
      int po = base + kr * 4 + r;
      if (po < cnt) {
        float* op = out + (size_t)po * 64 + am;
        op[0] = acc0[r]; op[16] = acc1[r]; op[32] = acc2[r]; op[48] = acc3[r];
        s0 += acc0[r]; q0 += acc0[r] * acc0[r];
        s1 += acc1[r]; q1 += acc1[r] * acc1[r];
        s2 += acc2[r]; q2 += acc2[r] * acc2[r];
        s3 += acc3[r]; q3 += acc3[r] * acc3[r];
      }
    }
    atomicAdd(&lsum[am], s0); atomicAdd(&lss[am], q0);
    atomicAdd(&lsum[am + 16], s1); atomicAdd(&lss[am + 16], q1);
    atomicAdd(&lsum[am + 32], s2); atomicAdd(&lss[am + 32], q2);
    atomicAdd(&lsum[am + 48], s3); atomicAdd(&lss[am + 48], q3);
  }
  __syncthreads();
  if (t < 64 && (lsum[t] != 0.f || lss[t] != 0.f)) {
    atomicAdd(&stats[t], lsum[t]);
    atomicAdd(&stats[64 + t], lss[t]);
  }
}

// ---- strided z conv (3-tap, K=64) via nbrz table, fused BN stats ----
__global__ __launch_bounds__(256) void k_convz(const u16* __restrict__ feats,
                                               const int* __restrict__ nbr,
                                               const u16* __restrict__ wfrag,
                                               float* __restrict__ out,
                                               const int* __restrict__ cntp,
                                               float* __restrict__ stats) {
  constexpr int KS = 2;
  __shared__ float lsum[64], lss[64];
  int cnt = *cntp;
  int t = threadIdx.x;
  if (t < 64) { lsum[t] = 0.f; lss[t] = 0.f; }
  __syncthreads();
  int lane = t & 63;
  int base = (blockIdx.x * 4 + (t >> 6)) * 16;
  bool active = base < cnt;
  int am = lane & 15;
  int kr = lane >> 4;
  int pt = base + am;
  bool vpt = active && (pt < cnt);
  f32x4 acc0 = {0.f, 0.f, 0.f, 0.f};
  f32x4 acc1 = acc0, acc2 = acc0, acc3 = acc0;
  if (active) {
    const int* np = nbr + (size_t)pt * 3;
    bf16x8 zf = {0, 0, 0, 0, 0, 0, 0, 0};
    int j = vpt ? np[0] : -1;
    bf16x8 a[KS], an[KS];
#pragma unroll
    for (int ks = 0; ks < KS; ++ks)
      a[ks] = (j >= 0) ? *(const bf16x8*)(feats + (size_t)j * 64 + ks * 32 + kr * 8) : zf;
    for (int o = 0; o < 3; ++o) {
      int jn = (o + 1 < 3 && vpt) ? np[o + 1] : -1;
#pragma unroll
      for (int ks = 0; ks < KS; ++ks)
        an[ks] = (jn >= 0) ? *(const bf16x8*)(feats + (size_t)jn * 64 + ks * 32 + kr * 8) : zf;
      const u16* bw = wfrag + (size_t)o * (KS * 2048) + lane * 8;
#pragma unroll
      for (int ks = 0; ks < KS; ++ks) {
        const u16* bwk = bw + ks * 2048;
        acc0 = __builtin_amdgcn_mfma_f32_16x16x32_bf16(a[ks], *(const bf16x8*)(bwk), acc0, 0, 0, 0);
        acc1 = __builtin_amdgcn_mfma_f32_16x16x32_bf16(a[ks], *(const bf16x8*)(bwk + 512), acc1, 0, 0, 0);
        acc2 = __builtin_amdgcn_mfma_f32_16x16x32_bf16(a[ks], *(const bf16x8*)(bwk + 1024), acc2, 0, 0, 0);
        acc3 = __builtin_amdgcn_mfma_f32_16x16x32_bf16(a[ks], *(const bf16x8*)(bwk + 1536), acc3, 0, 0, 0);
      }
#pragma unroll
      for (int ks = 0; ks < KS; ++ks) a[ks] = an[ks];
    }
    float s0 = 0.f, s1 = 0.f, s2 = 0.f, s3 = 0.f;
    float q0 = 0.f, q1 = 0.f, q2 = 0.f, q3 = 0.f;
#pragma unroll
    for (int r = 0; r < 4; ++r) {
      int po = base + kr * 4 + r;
      if (po < cnt) {
        float* op = out + (size_t)po * 64 + am;
        op[0] = acc0[r]; op[16] = acc1[r]; op[32] = acc2[r]; op[48] = acc3[r];
        s0 += acc0[r]; q0 += acc0[r] * acc0[r];
        s1 += acc1[r]; q1 += acc1[r] * acc1[r];
        s2 += acc2[r]; q2 += acc2[r] * acc2[r];
        s3 += acc3[r]; q3 += acc3[r] * acc3[r];
      }
    }
    atomicAdd(&lsum[am], s0); atomicAdd(&lss[am], q0);
    atomicAdd(&lsum[am + 16], s1); atomicAdd(&lss[am + 16], q1);
    atomicAdd(&lsum[am + 32], s2); atomicAdd(&lss[am + 32], q2);
    atomicAdd(&lsum[am + 48], s3); atomicAdd(&lss[am + 48], q3);
  }
  __syncthreads();
  if (t < 64 && (lsum[t] != 0.f || lss[t] != 0.f)) {
    atomicAdd(&stats[t], lsum[t]);
    atomicAdd(&stats[64 + t], lss[t]);
  }
}

// ---- BN normalize + ReLU -> bf16 ----
__global__ void k_norm(const float* __restrict__ x, const int* __restrict__ cntp,
                       const float* __restrict__ stats, const float* __restrict__ gamma,
                       const float* __restrict__ beta, u16* __restrict__ y) {
  int cnt = *cntp;
  int t = blockIdx.x * 256 + threadIdx.x;
  int i = t >> 6, c = t & 63;
  if (i >= cnt) return;
  float cf = (float)(cnt > 0 ? cnt : 1);
  float mean = stats[c] / cf;
  float var = stats[64 + c] / cf - mean * mean;
  float inv = rsqrtf(var + 1e-3f);
  float v = (x[(size_t)i * 64 + c] - mean) * inv * gamma[c] + beta[c];
  y[(size_t)i * 64 + c] = f2bf(fmaxf(v, 0.f));
}

// ---- fused: BN norm of level L + claim/downsample L -> L+1 ----
__global__ void k_norm_claim(const float* __restrict__ x, const int* __restrict__ cntp,
                             const float* __restrict__ stats, const float* __restrict__ gamma,
                             const float* __restrict__ beta, u16* __restrict__ y, int normCap,
                             const int* __restrict__ coordsIn, const int* __restrict__ idxin,
                             int Din, int Dout, int* __restrict__ claim,
                             int* __restrict__ coords_out, int* __restrict__ nbrz,
                             int* __restrict__ outcnt, int claimCap) {
  int t = blockIdx.x * 256 + threadIdx.x;
  int cnt = *cntp;
  if (t < normCap) {
    int i = t >> 6, c = t & 63;
    if (i >= cnt) return;
    float cf = (float)(cnt > 0 ? cnt : 1);
    float mean = stats[c] / cf;
    float var = stats[64 + c] / cf - mean * mean;
    float inv = rsqrtf(var + 1e-3f);
    float v = (x[(size_t)i * 64 + c] - mean) * inv * gamma[c] + beta[c];
    y[(size_t)i * 64 + c] = f2bf(fmaxf(v, 0.f));
    return;
  }
  int i = t - normCap;
  bool w0 = false, w1 = false;
  int pos0 = 0, pos1 = 0, oz0 = -1, oz1 = -1;
  int b = 0, z = 0, yy = 0, xx = 0;
  if (i < claimCap && i < cnt) {
    int4 cc = *(const int4*)(coordsIn + (size_t)i * 4);
    b = cc.x; z = cc.y; yy = cc.z; xx = cc.w;
    if (z & 1) {
      int oz = (z - 1) >> 1;
      if (oz < Dout) oz0 = oz;
    } else {
      int oz = z >> 1;
      if (oz < Dout) oz0 = oz;
      if (z >= 2) oz1 = oz - 1;
    }
    if (oz0 >= 0) {
      pos0 = ((b * Dout + oz0) * H_ + yy) * W_ + xx;
      w0 = (atomicCAS(&claim[pos0], -1, -2) == -1);
    }
    if (oz1 >= 0) {
      pos1 = ((b * Dout + oz1) * H_ + yy) * W_ + xx;
      w1 = (atomicCAS(&claim[pos1], -1, -2) == -1);
    }
  }
  u64 m0 = __ballot(w0), m1 = __ballot(w1);
  int c0 = __popcll(m0), c1 = __popcll(m1);
  int lane = threadIdx.x & 63;
  u64 lt = (lane == 63) ? 0x7FFFFFFFFFFFFFFFull : ((1ull << lane) - 1ull);
  int bse2 = 0;
  if (lane == 0 && (c0 + c1) > 0) bse2 = atomicAdd(outcnt, c0 + c1);
  bse2 = __shfl(bse2, 0);
  if (w0) {
    int id = bse2 + __popcll(m0 & lt);
    claim[pos0] = id;
    coords_out[id * 4 + 0] = b; coords_out[id * 4 + 1] = oz0;
    coords_out[id * 4 + 2] = yy; coords_out[id * 4 + 3] = xx;
    size_t bse = ((size_t)(b * Din + 2 * oz0) * H_ + yy) * W_ + xx;
    nbrz[id * 3 + 0] = idxin[bse];
    nbrz[id * 3 + 1] = idxin[bse + HW_];
    nbrz[id * 3 + 2] = idxin[bse + 2 * (size_t)HW_];
  }
  if (w1) {
    int id = bse2 + c0 + __popcll(m1 & lt);
    claim[pos1] = id;
    coords_out[id * 4 + 0] = b; coords_out[id * 4 + 1] = oz1;
    coords_out[id * 4 + 2] = yy; coords_out[id * 4 + 3] = xx;
    size_t bse = ((size_t)(b * Din + 2 * oz1) * H_ + yy) * W_ + xx;
    nbrz[id * 3 + 0] = idxin[bse];
    nbrz[id * 3 + 1] = idxin[bse + HW_];
    nbrz[id * 3 + 2] = idxin[bse + 2 * (size_t)HW_];
  }
}

// ---- dense output: BN+ReLU of level-2, full dense write (zero where empty) ----
__global__ void k_output(const float* __restrict__ x, const int* __restrict__ cntp,
                         const float* __restrict__ stats, const float* __restrict__ gamma,
                         const float* __restrict__ beta, const int* __restrict__ claim2,
                         float* __restrict__ out) {
  const int XQ = W_ / 4;
  int t = blockIdx.x * 256 + threadIdx.x;
  int total = B_ * 64 * D2_ * H_ * XQ;
  if (t >= total) return;
  int xq = t % XQ;
  int row = t / XQ;
  int y = row % H_;
  int r2 = row / H_;
  int oz = r2 % D2_;
  r2 /= D2_;
  int c = r2 & 63;
  int b = r2 >> 6;
  int cnt = *cntp;
  float cf = (float)(cnt > 0 ? cnt : 1);
  float mean = stats[c] / cf;
  float var = stats[64 + c] / cf - mean * mean;
  float inv = rsqrtf(var + 1e-3f);
  float g = gamma[c] * inv;
  float bb = beta[c] - mean * g;
  int pos = ((b * D2_ + oz) * H_ + y) * W_ + xq * 4;
  int4 ids = *(const int4*)(claim2 + pos);
  float4 v;
  v.x = (ids.x >= 0) ? fmaxf(x[(size_t)ids.x * 64 + c] * g + bb, 0.f) : 0.f;
  v.y = (ids.y >= 0) ? fmaxf(x[(size_t)ids.y * 64 + c] * g + bb, 0.f) : 0.f;
  v.z = (ids.z >= 0) ? fmaxf(x[(size_t)ids.z * 64 + c] * g + bb, 0.f) : 0.f;
  v.w = (ids.w >= 0) ? fmaxf(x[(size_t)ids.w * 64 + c] * g + bb, 0.f) : 0.f;
  *(float4*)(out + (size_t)row * W_ + xq * 4) = v;
}

extern "C" void kernel_launch(void* const* d_in, const int* in_sizes, int n_in,
                              void* d_out, int out_size, void* d_ws, size_t ws_size,
                              hipStream_t stream) {
  const int N = in_sizes[0] / 128;
  const int cap1 = 2 * N + 8;
  const int cap2 = 4 * N + 8;
  const int ng0 = (N + 15) / 16;
  const int ng1 = (cap1 + 15) / 16;

  char* ws = (char*)d_ws;
  size_t off = 0;
  auto alloc = [&](size_t bytes) -> void* {
    size_t o = off;
    off = (off + bytes + 255) & ~(size_t)255;
    return (void*)(ws + o);
  };

  int* ctrl = (int*)alloc(16);
  float* stats = (float*)alloc(768 * 4);
  size_t fill_beg = off;
  int* idx0 = (int*)alloc((size_t)B_ * D0_ * HW_ * 4);
  int* idx1 = (int*)alloc((size_t)B_ * D1_ * HW_ * 4);
  int* claim2 = (int*)alloc((size_t)B_ * D2_ * HW_ * 4);
  size_t fill_end = off;
  size_t zero_beg = off;
  u32* gmask0 = (u32*)alloc((size_t)ng0 * 4);
  u32* gmask1 = (u32*)alloc((size_t)ng1 * 4);
  size_t zero_end = off;
  int* nbr0 = (int*)alloc((size_t)ng0 * 432 * 4);
  int* nbr1 = (int*)alloc((size_t)ng1 * 432 * 4);
  int* nbrz1 = (int*)alloc((size_t)cap1 * 3 * 4);
  int* nbrz2 = (int*)alloc((size_t)cap2 * 3 * 4);
  int* coords1 = (int*)alloc((size_t)cap1 * 4 * 4);
  int* coords2 = (int*)alloc((size_t)cap2 * 4 * 4);
  float* xbuf = (float*)alloc((size_t)cap2 * 64 * 4);
  u16* fb = (u16*)alloc((size_t)N * 128 * 2);
  u16* y0 = (u16*)alloc((size_t)N * 64 * 2);
  u16* y1 = (u16*)alloc((size_t)cap1 * 64 * 2);
  u16* y2 = (u16*)alloc((size_t)cap1 * 64 * 2);
  u16* y3 = (u16*)alloc((size_t)cap1 * 64 * 2);
  u16* wf0 = (u16*)alloc((size_t)27 * 4 * 2048 * 2);
  u16* wf1a = (u16*)alloc((size_t)27 * 2 * 2048 * 2);
  u16* wf1b = (u16*)alloc((size_t)27 * 2 * 2048 * 2);
  u16* wfz1 = (u16*)alloc((size_t)3 * 2 * 2048 * 2);
  u16* wfz2 = (u16*)alloc((size_t)3 * 2 * 2048 * 2);

  const int* coors = (const int*)d_in[1];
  auto gr = [](long n) { return dim3((unsigned)((n + 255) / 256)); };

  // 1: setup
  int nfill16 = (int)((fill_end - fill_beg) / 16);
  int nzero16 = (int)((zero_end - zero_beg) / 16);
  k_setup<<<gr((long)nfill16 + nzero16 + 771), 256, 0, stream>>>(
      ctrl, stats, (uint4*)(ws + fill_beg), nfill16, (uint4*)(ws + zero_beg), nzero16, N);

  // 2: prep
  long prepTotal = (long)N * 128 + 221184 + 110592 + 110592 + 12288 + 12288 + N;
  k_prep<<<gr(prepTotal), 256, 0, stream>>>((const float*)d_in[0], (const float*)d_in[3],
                                            (const float*)d_in[9], (const float*)d_in[12],
                                            (const float*)d_in[6], (const float*)d_in[15],
                                            coors, fb, wf0, wf1a, wf1b, wfz1, wfz2, idx0, N);

  // 3: level-0 neighbor table + masks
  k_nbr<<<gr((long)ng0 * 432), 256, 0, stream>>>(coors, ctrl + 0, idx0, D0_, nbr0, gmask0, ng0);

  // 4: level-0 subm conv (128->64), active offsets only
  k_conv27<128><<<dim3((N + 63) / 64), 256, 0, stream>>>(fb, nbr0, gmask0, wf0, xbuf,
                                                         ctrl + 0, stats + 0);
  // 5: norm y0 + claim level1
  k_norm_claim<<<gr((long)N * 64 + N), 256, 0, stream>>>(
      xbuf, ctrl + 0, stats + 0, (const float*)d_in[4], (const float*)d_in[5], y0, N * 64,
      coors, idx0, D0_, D1_, idx1, coords1, nbrz1, ctrl + 1, N);

  // 6: level-1 neighbor table + masks (used by both subm convs)
  k_nbr<<<gr((long)ng1 * 432), 256, 0, stream>>>(coords1, ctrl + 1, idx1, D1_, nbr1, gmask1, ng1);

  // 7: z-conv 1 + stats
  k_convz<<<dim3((cap1 + 63) / 64), 256, 0, stream>>>(y0, nbrz1, wfz1, xbuf, ctrl + 1, stats + 128);
  // 8: norm y1
  k_norm<<<gr((long)cap1 * 64), 256, 0, stream>>>(xbuf, ctrl + 1, stats + 128,
                                                  (const float*)d_in[7], (const float*)d_in[8], y1);

  // 9: level-1 subm conv a
  k_conv27<64><<<dim3((cap1 + 63) / 64), 256, 0, stream>>>(y1, nbr1, gmask1, wf1a, xbuf,
                                                           ctrl + 1, stats + 256);
  // 10: norm y2
  k_norm<<<gr((long)cap1 * 64), 256, 0, stream>>>(xbuf, ctrl + 1, stats + 256,
                                                  (const float*)d_in[10], (const float*)d_in[11], y2);

  // 11: level-1 subm conv b
  k_conv27<64><<<dim3((cap1 + 63) / 64), 256, 0, stream>>>(y2, nbr1, gmask1, wf1b, xbuf,
                                                           ctrl + 1, stats + 384);
  // 12: norm y3 + claim level2
  k_norm_claim<<<gr((long)cap1 * 64 + cap1), 256, 0, stream>>>(
      xbuf, ctrl + 1, stats + 384, (const float*)d_in[13], (const float*)d_in[14], y3, cap1 * 64,
      coords1, idx1, D1_, D2_, claim2, coords2, nbrz2, ctrl + 2, cap1);

  // 13: z-conv 2 + stats
  k_convz<<<dim3((cap2 + 63) / 64), 256, 0, stream>>>(y3, nbrz2, wfz2, xbuf, ctrl + 2, stats + 512);

  // 14: dense output
  long outThreads = (long)B_ * 64 * D2_ * H_ * (W_ / 4);
  k_output<<<gr(outThreads), 256, 0, stream>>>(xbuf, ctrl + 2, stats + 512,
                                               (const float*)d_in[16], (const float*)d_in[17],
                                               claim2, (float*)d_out);
}

// Round 7
// 381.943 us; speedup vs baseline: 2.3125x; 1.1981x over previous
//
#include <hip/hip_runtime.h>

typedef unsigned short u16;
typedef unsigned int u32;
typedef unsigned long long u64;
typedef __attribute__((ext_vector_type(8))) short bf16x8;
typedef __attribute__((ext_vector_type(4))) float f32x4;

#define H_ 200
#define W_ 176
#define HW_ (200 * 176)
#define D0_ 41
#define D1_ 20
#define D2_ 9
#define B_ 2

__device__ __forceinline__ u16 f2bf(float f) {
  union { float f; u32 u; } c; c.f = f;
  u32 u = c.u;
  u32 r = (u + 0x7fffu + ((u >> 16) & 1u)) >> 16;
  return (u16)r;
}

// ---- boot1: -1 fill of idx/claim maps + ctrl + striped stats zero ----
__global__ void k_boot1(int* __restrict__ ctrl, float* __restrict__ stats,
                        uint4* __restrict__ fillp, int nfill16, int N) {
  int t = blockIdx.x * 256 + threadIdx.x;
  if (t < nfill16) {
    uint4 v;
    v.x = 0xFFFFFFFFu; v.y = 0xFFFFFFFFu; v.z = 0xFFFFFFFFu; v.w = 0xFFFFFFFFu;
    fillp[t] = v;
    return;
  }
  t -= nfill16;
  if (t < 3) ctrl[t] = (t == 0) ? N : 0;
  else if (t < 3 + 2560) stats[t - 3] = 0.f;
}

// ---- weight repack: (NOFF,K,64) fp32 -> bf16 fragment order [o][ks][nt][lane][8] ----
__device__ __forceinline__ void repack1(const float* __restrict__ w, u16* __restrict__ frag,
                                        int K, int t) {
  int j = t & 7;
  int lane = (t >> 3) & 63;
  int nt = (t >> 9) & 3;
  int rest = t >> 11;
  int KS = K / 32;
  int ks = rest % KS;
  int o = rest / KS;
  int k = ks * 32 + (lane >> 4) * 8 + j;
  int n = nt * 16 + (lane & 15);
  frag[t] = f2bf(w[((size_t)o * K + k) * 64 + n]);
}

// ---- boot2: feats fp32->bf16, 5 weight repacks, idx0 scatter ----
__global__ void k_boot2(const float* __restrict__ feats, const float* __restrict__ w0s,
                        const float* __restrict__ w1as, const float* __restrict__ w1bs,
                        const float* __restrict__ wz1s, const float* __restrict__ wz2s,
                        const int* __restrict__ coors,
                        u16* __restrict__ fb, u16* __restrict__ wf0, u16* __restrict__ wf1a,
                        u16* __restrict__ wf1b, u16* __restrict__ wfz1, u16* __restrict__ wfz2,
                        int* __restrict__ idx0, int N) {
  int t = blockIdx.x * 256 + threadIdx.x;
  int NC = N * 128;
  if (t < NC) { fb[t] = f2bf(feats[t]); return; }
  t -= NC;
  if (t < 221184) { repack1(w0s, wf0, 128, t); return; }
  t -= 221184;
  if (t < 110592) { repack1(w1as, wf1a, 64, t); return; }
  t -= 110592;
  if (t < 110592) { repack1(w1bs, wf1b, 64, t); return; }
  t -= 110592;
  if (t < 12288) { repack1(wz1s, wfz1, 64, t); return; }
  t -= 12288;
  if (t < 12288) { repack1(wz2s, wfz2, 64, t); return; }
  t -= 12288;
  if (t < N) {
    int b = coors[t * 4], z = coors[t * 4 + 1], y = coors[t * 4 + 2], x = coors[t * 4 + 3];
    idx0[((size_t)(b * D0_ + z) * H_ + y) * W_ + x] = t;
  }
}

// ---- wave-0 claim: downsample level L -> L+1 for 64 points [base64, base64+64) ----
__device__ __forceinline__ void claim_ep(int t, int base64, int cnt,
                                         const int* __restrict__ coordsIn,
                                         const int* __restrict__ idxin, int Din, int Dout,
                                         int* __restrict__ claim, int* __restrict__ coords_out,
                                         int* __restrict__ nbrzN, int* __restrict__ outcnt) {
  int i = base64 + t;
  bool w0 = false, w1 = false;
  int pos0 = 0, pos1 = 0, oz0 = -1, oz1 = -1;
  int b = 0, z = 0, yy = 0, xx = 0;
  if (i < cnt) {
    int4 cc = *(const int4*)(coordsIn + (size_t)i * 4);
    b = cc.x; z = cc.y; yy = cc.z; xx = cc.w;
    if (z & 1) {
      int oz = (z - 1) >> 1;
      if (oz < Dout) oz0 = oz;
    } else {
      int oz = z >> 1;
      if (oz < Dout) oz0 = oz;
      if (z >= 2) oz1 = oz - 1;
    }
    if (oz0 >= 0) {
      pos0 = ((b * Dout + oz0) * H_ + yy) * W_ + xx;
      w0 = (atomicCAS(&claim[pos0], -1, -2) == -1);
    }
    if (oz1 >= 0) {
      pos1 = ((b * Dout + oz1) * H_ + yy) * W_ + xx;
      w1 = (atomicCAS(&claim[pos1], -1, -2) == -1);
    }
  }
  u64 m0 = __ballot(w0), m1 = __ballot(w1);
  int c0 = __popcll(m0), c1 = __popcll(m1);
  int lane = t & 63;
  u64 lt = (lane == 63) ? 0x7FFFFFFFFFFFFFFFull : ((1ull << lane) - 1ull);
  int bse2 = 0;
  if (lane == 0 && (c0 + c1) > 0) bse2 = atomicAdd(outcnt, c0 + c1);
  bse2 = __shfl(bse2, 0);
  if (w0) {
    int id = bse2 + __popcll(m0 & lt);
    claim[pos0] = id;
    coords_out[id * 4 + 0] = b; coords_out[id * 4 + 1] = oz0;
    coords_out[id * 4 + 2] = yy; coords_out[id * 4 + 3] = xx;
    size_t bse = ((size_t)(b * Din + 2 * oz0) * H_ + yy) * W_ + xx;
    nbrzN[id * 3 + 0] = idxin[bse];
    nbrzN[id * 3 + 1] = idxin[bse + HW_];
    nbrzN[id * 3 + 2] = idxin[bse + 2 * (size_t)HW_];
  }
  if (w1) {
    int id = bse2 + c0 + __popcll(m1 & lt);
    claim[pos1] = id;
    coords_out[id * 4 + 0] = b; coords_out[id * 4 + 1] = oz1;
    coords_out[id * 4 + 2] = yy; coords_out[id * 4 + 3] = xx;
    size_t bse = ((size_t)(b * Din + 2 * oz1) * H_ + yy) * W_ + xx;
    nbrzN[id * 3 + 0] = idxin[bse];
    nbrzN[id * 3 + 1] = idxin[bse + HW_];
    nbrzN[id * 3 + 2] = idxin[bse + 2 * (size_t)HW_];
  }
}

// ---- conv0: LDS nbr-gen + K=128 subm conv (bf16 A) + striped stats + claim1 ----
__global__ __launch_bounds__(256) void k_conv0(const u16* __restrict__ feats,
                                               const int* __restrict__ coords,
                                               const int* __restrict__ idxmap,
                                               const u16* __restrict__ wfrag,
                                               float* __restrict__ out, int cnt,
                                               float* __restrict__ statsL,
                                               int* __restrict__ claim, int* __restrict__ coords_out,
                                               int* __restrict__ nbrzN, int* __restrict__ outcnt) {
  constexpr int KS = 4;
  __shared__ int snbr[1728];
  __shared__ u32 smask[4];
  __shared__ float lsum[64], lss[64];
  int t = threadIdx.x;
  if (t < 64) { lsum[t] = 0.f; lss[t] = 0.f; }
  if (t < 4) smask[t] = 0;
  __syncthreads();
  int blockBase = blockIdx.x * 64;
  // phase 1: neighbor table into LDS
  for (int r = t; r < 1728; r += 256) {
    int g = r / 432;
    int rr = r - g * 432;
    int o = rr >> 4;
    int i = blockBase + g * 16 + (rr & 15);
    int j = -1;
    if (i < cnt) {
      int4 cc = *(const int4*)(coords + (size_t)i * 4);
      int nz = cc.y + o / 9 - 1, ny = cc.z + (o / 3) % 3 - 1, nx = cc.w + o % 3 - 1;
      if ((u32)nz < (u32)D0_ && (u32)ny < (u32)H_ && (u32)nx < (u32)W_)
        j = idxmap[((size_t)(cc.x * D0_ + nz) * H_ + ny) * W_ + nx];
    }
    snbr[r] = j;
    if (j >= 0) atomicOr(&smask[g], 1u << o);
  }
  __syncthreads();
  // phase 2: conv
  int lane = t & 63;
  int wg = t >> 6;
  int base = blockBase + wg * 16;
  int am = lane & 15, kr = lane >> 4;
  f32x4 acc0 = {0.f, 0.f, 0.f, 0.f};
  f32x4 acc1 = acc0, acc2 = acc0, acc3 = acc0;
  if (base < cnt) {
    u32 mask = smask[wg];
    const int* nb = snbr + wg * 432 + am;
    bf16x8 zf = {0, 0, 0, 0, 0, 0, 0, 0};
    bf16x8 a[KS], an[KS];
    if (mask) {
      int o = __builtin_ctz(mask); mask &= mask - 1;
      int j = nb[o * 16];
#pragma unroll
      for (int ks = 0; ks < KS; ++ks)
        a[ks] = (j >= 0) ? *(const bf16x8*)(feats + (size_t)j * 128 + ks * 32 + kr * 8) : zf;
      while (true) {
        int on = -1, jn = -1;
        if (mask) { on = __builtin_ctz(mask); mask &= mask - 1; jn = nb[on * 16]; }
#pragma unroll
        for (int ks = 0; ks < KS; ++ks)
          an[ks] = (jn >= 0) ? *(const bf16x8*)(feats + (size_t)jn * 128 + ks * 32 + kr * 8) : zf;
        const u16* bw = wfrag + (size_t)o * (KS * 2048) + lane * 8;
#pragma unroll
        for (int ks = 0; ks < KS; ++ks) {
          const u16* bwk = bw + ks * 2048;
          acc0 = __builtin_amdgcn_mfma_f32_16x16x32_bf16(a[ks], *(const bf16x8*)(bwk), acc0, 0, 0, 0);
          acc1 = __builtin_amdgcn_mfma_f32_16x16x32_bf16(a[ks], *(const bf16x8*)(bwk + 512), acc1, 0, 0, 0);
          acc2 = __builtin_amdgcn_mfma_f32_16x16x32_bf16(a[ks], *(const bf16x8*)(bwk + 1024), acc2, 0, 0, 0);
          acc3 = __builtin_amdgcn_mfma_f32_16x16x32_bf16(a[ks], *(const bf16x8*)(bwk + 1536), acc3, 0, 0, 0);
        }
        if (on < 0) break;
        o = on;
#pragma unroll
        for (int ks = 0; ks < KS; ++ks) a[ks] = an[ks];
      }
    }
    float s0 = 0.f, s1 = 0.f, s2 = 0.f, s3 = 0.f;
    float q0 = 0.f, q1 = 0.f, q2 = 0.f, q3 = 0.f;
#pragma unroll
    for (int r = 0; r < 4; ++r) {
      int po = base + kr * 4 + r;
      if (po < cnt) {
        float* op = out + (size_t)po * 64 + am;
        op[0] = acc0[r]; op[16] = acc1[r]; op[32] = acc2[r]; op[48] = acc3[r];
        s0 += acc0[r]; q0 += acc0[r] * acc0[r];
        s1 += acc1[r]; q1 += acc1[r] * acc1[r];
        s2 += acc2[r]; q2 += acc2[r] * acc2[r];
        s3 += acc3[r]; q3 += acc3[r] * acc3[r];
      }
    }
    atomicAdd(&lsum[am], s0); atomicAdd(&lss[am], q0);
    atomicAdd(&lsum[am + 16], s1); atomicAdd(&lss[am + 16], q1);
    atomicAdd(&lsum[am + 32], s2); atomicAdd(&lss[am + 32], q2);
    atomicAdd(&lsum[am + 48], s3); atomicAdd(&lss[am + 48], q3);
  }
  __syncthreads();
  if (t < 64) {
    float s = lsum[t], q = lss[t];
    if (s != 0.f || q != 0.f) {
      float* dst = statsL + (blockIdx.x & 3) * 128;
      atomicAdd(&dst[t], s);
      atomicAdd(&dst[64 + t], q);
    }
    claim_ep(t, blockBase, cnt, coords, idxmap, D0_, D1_, claim, coords_out, nbrzN, outcnt);
  }
}

// ---- BN precompute into LDS (striped stats) ----
__device__ __forceinline__ void bn_pre(const float* __restrict__ statsIn, int cntN,
                                       const float* __restrict__ gamma,
                                       const float* __restrict__ beta,
                                       float* __restrict__ ggs, float* __restrict__ bbs, int t) {
  if (t < 64) {
    float s = 0.f, q = 0.f;
#pragma unroll
    for (int k = 0; k < 4; ++k) { s += statsIn[k * 128 + t]; q += statsIn[k * 128 + 64 + t]; }
    float cf = (float)(cntN > 0 ? cntN : 1);
    float mean = s / cf;
    float var = q / cf - mean * mean;
    float inv = rsqrtf(var + 1e-3f);
    float g = gamma[t] * inv;
    ggs[t] = g;
    bbs[t] = beta[t] - mean * g;
  }
}

// ---- strided z conv (K=64), A = BN-inline from fp32; optional nbr-gen + claim epilogues ----
__global__ __launch_bounds__(256) void k_convz(
    const float* __restrict__ xp, const int* __restrict__ nbrz_in,
    const u16* __restrict__ wfrag, const float* __restrict__ statsIn,
    const int* __restrict__ cntNormP, const float* __restrict__ gamma,
    const float* __restrict__ beta, float* __restrict__ out, const int* __restrict__ cntp,
    float* __restrict__ statsOut,
    const int* __restrict__ coordsL, const int* __restrict__ idxL, int DL,
    int* __restrict__ nbrT, u32* __restrict__ gmaskT,
    int Dnext, int* __restrict__ claimN, int* __restrict__ coordsN,
    int* __restrict__ nbrzN, int* __restrict__ cntN2) {
  int cnt = *cntp;
  int blockBase = blockIdx.x * 64;
  if (blockBase >= cnt) return;
  __shared__ float lsum[64], lss[64], ggs[64], bbs[64];
  __shared__ u32 smask[4];
  int t = threadIdx.x;
  if (t < 64) { lsum[t] = 0.f; lss[t] = 0.f; }
  if (t < 4) smask[t] = 0;
  bn_pre(statsIn, *cntNormP, gamma, beta, ggs, bbs, t);
  __syncthreads();
  // optional: level-L 27-neighbor table gen (global, reused by subm convs)
  if (nbrT) {
    for (int r = t; r < 1728; r += 256) {
      int g = r / 432;
      int rr = r - g * 432;
      int o = rr >> 4;
      int i = blockBase + g * 16 + (rr & 15);
      int j = -1;
      if (i < cnt) {
        int4 cc = *(const int4*)(coordsL + (size_t)i * 4);
        int nz = cc.y + o / 9 - 1, ny = cc.z + (o / 3) % 3 - 1, nx = cc.w + o % 3 - 1;
        if ((u32)nz < (u32)DL && (u32)ny < (u32)H_ && (u32)nx < (u32)W_)
          j = idxL[((size_t)(cc.x * DL + nz) * H_ + ny) * W_ + nx];
      }
      nbrT[(size_t)(blockIdx.x * 4 + g) * 432 + rr] = j;
      if (j >= 0) atomicOr(&smask[g], 1u << o);
    }
  }
  int lane = t & 63;
  int wg = t >> 6;
  int base = blockBase + wg * 16;
  int am = lane & 15, kr = lane >> 4;
  float gr_[16], br_[16];
#pragma unroll
  for (int ks = 0; ks < 2; ++ks)
#pragma unroll
    for (int e = 0; e < 8; ++e) {
      int c = ks * 32 + kr * 8 + e;
      gr_[ks * 8 + e] = ggs[c];
      br_[ks * 8 + e] = bbs[c];
    }
  f32x4 acc0 = {0.f, 0.f, 0.f, 0.f};
  f32x4 acc1 = acc0, acc2 = acc0, acc3 = acc0;
  if (base < cnt) {
    int pt = base + am;
    bool vpt = pt < cnt;
    const int* np = nbrz_in + (size_t)pt * 3;
    bf16x8 zf = {0, 0, 0, 0, 0, 0, 0, 0};
    bf16x8 a[2], an[2];
    auto buildA = [&](int j, bf16x8* aa) {
      if (j >= 0) {
        const float* src = xp + (size_t)j * 64 + kr * 8;
#pragma unroll
        for (int ks = 0; ks < 2; ++ks) {
          float4 v0 = *(const float4*)(src + ks * 32);
          float4 v1 = *(const float4*)(src + ks * 32 + 4);
          bf16x8 w;
          w[0] = (short)f2bf(fmaxf(v0.x * gr_[ks * 8 + 0] + br_[ks * 8 + 0], 0.f));
          w[1] = (short)f2bf(fmaxf(v0.y * gr_[ks * 8 + 1] + br_[ks * 8 + 1], 0.f));
          w[2] = (short)f2bf(fmaxf(v0.z * gr_[ks * 8 + 2] + br_[ks * 8 + 2], 0.f));
          w[3] = (short)f2bf(fmaxf(v0.w * gr_[ks * 8 + 3] + br_[ks * 8 + 3], 0.f));
          w[4] = (short)f2bf(fmaxf(v1.x * gr_[ks * 8 + 4] + br_[ks * 8 + 4], 0.f));
          w[5] = (short)f2bf(fmaxf(v1.y * gr_[ks * 8 + 5] + br_[ks * 8 + 5], 0.f));
          w[6] = (short)f2bf(fmaxf(v1.z * gr_[ks * 8 + 6] + br_[ks * 8 + 6], 0.f));
          w[7] = (short)f2bf(fmaxf(v1.w * gr_[ks * 8 + 7] + br_[ks * 8 + 7], 0.f));
          aa[ks] = w;
        }
      } else { aa[0] = zf; aa[1] = zf; }
    };
    int j = vpt ? np[0] : -1;
    buildA(j, a);
    for (int o = 0; o < 3; ++o) {
      int jn = (o + 1 < 3 && vpt) ? np[o + 1] : -1;
      buildA(jn, an);
      const u16* bw = wfrag + (size_t)o * 4096 + lane * 8;
#pragma unroll
      for (int ks = 0; ks < 2; ++ks) {
        const u16* bwk = bw + ks * 2048;
        acc0 = __builtin_amdgcn_mfma_f32_16x16x32_bf16(a[ks], *(const bf16x8*)(bwk), acc0, 0, 0, 0);
        acc1 = __builtin_amdgcn_mfma_f32_16x16x32_bf16(a[ks], *(const bf16x8*)(bwk + 512), acc1, 0, 0, 0);
        acc2 = __builtin_amdgcn_mfma_f32_16x16x32_bf16(a[ks], *(const bf16x8*)(bwk + 1024), acc2, 0, 0, 0);
        acc3 = __builtin_amdgcn_mfma_f32_16x16x32_bf16(a[ks], *(const bf16x8*)(bwk + 1536), acc3, 0, 0, 0);
      }
      a[0] = an[0]; a[1] = an[1];
    }
    float s0 = 0.f, s1 = 0.f, s2 = 0.f, s3 = 0.f;
    float q0 = 0.f, q1 = 0.f, q2 = 0.f, q3 = 0.f;
#pragma unroll
    for (int r = 0; r < 4; ++r) {
      int po = base + kr * 4 + r;
      if (po < cnt) {
        float* op = out + (size_t)po * 64 + am;
        op[0] = acc0[r]; op[16] = acc1[r]; op[32] = acc2[r]; op[48] = acc3[r];
        s0 += acc0[r]; q0 += acc0[r] * acc0[r];
        s1 += acc1[r]; q1 += acc1[r] * acc1[r];
        s2 += acc2[r]; q2 += acc2[r] * acc2[r];
        s3 += acc3[r]; q3 += acc3[r] * acc3[r];
      }
    }
    atomicAdd(&lsum[am], s0); atomicAdd(&lss[am], q0);
    atomicAdd(&lsum[am + 16], s1); atomicAdd(&lss[am + 16], q1);
    atomicAdd(&lsum[am + 32], s2); atomicAdd(&lss[am + 32], q2);
    atomicAdd(&lsum[am + 48], s3); atomicAdd(&lss[am + 48], q3);
  }
  __syncthreads();
  if (nbrT && t < 4) gmaskT[blockIdx.x * 4 + t] = smask[t];
  if (t < 64) {
    float s = lsum[t], q = lss[t];
    if (s != 0.f || q != 0.f) {
      float* dst = statsOut + (blockIdx.x & 3) * 128;
      atomicAdd(&dst[t], s);
      atomicAdd(&dst[64 + t], q);
    }
    if (claimN)
      claim_ep(t, blockBase, cnt, coordsL, idxL, DL, Dnext, claimN, coordsN, nbrzN, cntN2);
  }
}

// ---- subm conv level 1 (K=64), A = BN-inline from fp32, masked active offsets ----
__global__ __launch_bounds__(256) void k_conv1(
    const float* __restrict__ xp, const int* __restrict__ nbrT, const u32* __restrict__ gmaskT,
    const u16* __restrict__ wfrag, const float* __restrict__ statsIn,
    const int* __restrict__ cntNormP, const float* __restrict__ gamma,
    const float* __restrict__ beta, float* __restrict__ out, const int* __restrict__ cntp,
    float* __restrict__ statsOut) {
  int cnt = *cntp;
  int blockBase = blockIdx.x * 64;
  if (blockBase >= cnt) return;
  __shared__ float lsum[64], lss[64], ggs[64], bbs[64];
  int t = threadIdx.x;
  if (t < 64) { lsum[t] = 0.f; lss[t] = 0.f; }
  bn_pre(statsIn, *cntNormP, gamma, beta, ggs, bbs, t);
  __syncthreads();
  int lane = t & 63;
  int wg = t >> 6;
  int g = blockIdx.x * 4 + wg;
  int base = blockBase + wg * 16;
  int am = lane & 15, kr = lane >> 4;
  float gr_[16], br_[16];
#pragma unroll
  for (int ks = 0; ks < 2; ++ks)
#pragma unroll
    for (int e = 0; e < 8; ++e) {
      int c = ks * 32 + kr * 8 + e;
      gr_[ks * 8 + e] = ggs[c];
      br_[ks * 8 + e] = bbs[c];
    }
  f32x4 acc0 = {0.f, 0.f, 0.f, 0.f};
  f32x4 acc1 = acc0, acc2 = acc0, acc3 = acc0;
  if (base < cnt) {
    u32 mask = gmaskT[g];
    const int* nb = nbrT + (size_t)g * 432 + am;
    bf16x8 zf = {0, 0, 0, 0, 0, 0, 0, 0};
    bf16x8 a[2], an[2];
    auto buildA = [&](int j, bf16x8* aa) {
      if (j >= 0) {
        const float* src = xp + (size_t)j * 64 + kr * 8;
#pragma unroll
        for (int ks = 0; ks < 2; ++ks) {
          float4 v0 = *(const float4*)(src + ks * 32);
          float4 v1 = *(const float4*)(src + ks * 32 + 4);
          bf16x8 w;
          w[0] = (short)f2bf(fmaxf(v0.x * gr_[ks * 8 + 0] + br_[ks * 8 + 0], 0.f));
          w[1] = (short)f2bf(fmaxf(v0.y * gr_[ks * 8 + 1] + br_[ks * 8 + 1], 0.f));
          w[2] = (short)f2bf(fmaxf(v0.z * gr_[ks * 8 + 2] + br_[ks * 8 + 2], 0.f));
          w[3] = (short)f2bf(fmaxf(v0.w * gr_[ks * 8 + 3] + br_[ks * 8 + 3], 0.f));
          w[4] = (short)f2bf(fmaxf(v1.x * gr_[ks * 8 + 4] + br_[ks * 8 + 4], 0.f));
          w[5] = (short)f2bf(fmaxf(v1.y * gr_[ks * 8 + 5] + br_[ks * 8 + 5], 0.f));
          w[6] = (short)f2bf(fmaxf(v1.z * gr_[ks * 8 + 6] + br_[ks * 8 + 6], 0.f));
          w[7] = (short)f2bf(fmaxf(v1.w * gr_[ks * 8 + 7] + br_[ks * 8 + 7], 0.f));
          aa[ks] = w;
        }
      } else { aa[0] = zf; aa[1] = zf; }
    };
    if (mask) {
      int o = __builtin_ctz(mask); mask &= mask - 1;
      int j = nb[o * 16];
      buildA(j, a);
      while (true) {
        int on = -1, jn = -1;
        if (mask) { on = __builtin_ctz(mask); mask &= mask - 1; jn = nb[on * 16]; }
        buildA(jn, an);
        const u16* bw = wfrag + (size_t)o * 4096 + lane * 8;
#pragma unroll
        for (int ks = 0; ks < 2; ++ks) {
          const u16* bwk = bw + ks * 2048;
          acc0 = __builtin_amdgcn_mfma_f32_16x16x32_bf16(a[ks], *(const bf16x8*)(bwk), acc0, 0, 0, 0);
          acc1 = __builtin_amdgcn_mfma_f32_16x16x32_bf16(a[ks], *(const bf16x8*)(bwk + 512), acc1, 0, 0, 0);
          acc2 = __builtin_amdgcn_mfma_f32_16x16x32_bf16(a[ks], *(const bf16x8*)(bwk + 1024), acc2, 0, 0, 0);
          acc3 = __builtin_amdgcn_mfma_f32_16x16x32_bf16(a[ks], *(const bf16x8*)(bwk + 1536), acc3, 0, 0, 0);
        }
        if (on < 0) break;
        o = on;
        a[0] = an[0]; a[1] = an[1];
      }
    }
    float s0 = 0.f, s1 = 0.f, s2 = 0.f, s3 = 0.f;
    float q0 = 0.f, q1 = 0.f, q2 = 0.f, q3 = 0.f;
#pragma unroll
    for (int r = 0; r < 4; ++r) {
      int po = base + kr * 4 + r;
      if (po < cnt) {
        float* op = out + (size_t)po * 64 + am;
        op[0] = acc0[r]; op[16] = acc1[r]; op[32] = acc2[r]; op[48] = acc3[r];
        s0 += acc0[r]; q0 += acc0[r] * acc0[r];
        s1 += acc1[r]; q1 += acc1[r] * acc1[r];
        s2 += acc2[r]; q2 += acc2[r] * acc2[r];
        s3 += acc3[r]; q3 += acc3[r] * acc3[r];
      }
    }
    atomicAdd(&lsum[am], s0); atomicAdd(&lss[am], q0);
    atomicAdd(&lsum[am + 16], s1); atomicAdd(&lss[am + 16], q1);
    atomicAdd(&lsum[am + 32], s2); atomicAdd(&lss[am + 32], q2);
    atomicAdd(&lsum[am + 48], s3); atomicAdd(&lss[am + 48], q3);
  }
  __syncthreads();
  if (t < 64) {
    float s = lsum[t], q = lss[t];
    if (s != 0.f || q != 0.f) {
      float* dst = statsOut + (blockIdx.x & 3) * 128;
      atomicAdd(&dst[t], s);
      atomicAdd(&dst[64 + t], q);
    }
  }
}

// ---- dense output: BN4+ReLU inline, zero elsewhere ----
__global__ void k_output(const float* __restrict__ x, const int* __restrict__ cntp,
                         const float* __restrict__ stats, const float* __restrict__ gamma,
                         const float* __restrict__ beta, const int* __restrict__ claim2,
                         float* __restrict__ out) {
  const int XQ = W_ / 4;
  int t = blockIdx.x * 256 + threadIdx.x;
  int total = B_ * 64 * D2_ * H_ * XQ;
  if (t >= total) return;
  int xq = t % XQ;
  int row = t / XQ;
  int y = row % H_;
  int r2 = row / H_;
  int oz = r2 % D2_;
  r2 /= D2_;
  int c = r2 & 63;
  int b = r2 >> 6;
  int cnt = *cntp;
  float s = 0.f, q = 0.f;
#pragma unroll
  for (int k = 0; k < 4; ++k) { s += stats[k * 128 + c]; q += stats[k * 128 + 64 + c]; }
  float cf = (float)(cnt > 0 ? cnt : 1);
  float mean = s / cf;
  float var = q / cf - mean * mean;
  float inv = rsqrtf(var + 1e-3f);
  float g = gamma[c] * inv;
  float bb = beta[c] - mean * g;
  int pos = ((b * D2_ + oz) * H_ + y) * W_ + xq * 4;
  int4 ids = *(const int4*)(claim2 + pos);
  float4 v;
  v.x = (ids.x >= 0) ? fmaxf(x[(size_t)ids.x * 64 + c] * g + bb, 0.f) : 0.f;
  v.y = (ids.y >= 0) ? fmaxf(x[(size_t)ids.y * 64 + c] * g + bb, 0.f) : 0.f;
  v.z = (ids.z >= 0) ? fmaxf(x[(size_t)ids.z * 64 + c] * g + bb, 0.f) : 0.f;
  v.w = (ids.w >= 0) ? fmaxf(x[(size_t)ids.w * 64 + c] * g + bb, 0.f) : 0.f;
  *(float4*)(out + (size_t)row * W_ + xq * 4) = v;
}

extern "C" void kernel_launch(void* const* d_in, const int* in_sizes, int n_in,
                              void* d_out, int out_size, void* d_ws, size_t ws_size,
                              hipStream_t stream) {
  const int N = in_sizes[0] / 128;
  const int cap1 = 2 * N + 8;
  const int cap2 = 4 * N + 8;
  const int ng1 = (cap1 + 15) / 16;

  char* ws = (char*)d_ws;
  size_t off = 0;
  auto alloc = [&](size_t bytes) -> void* {
    size_t o = off;
    off = (off + bytes + 255) & ~(size_t)255;
    return (void*)(ws + o);
  };

  int* ctrl = (int*)alloc(16);
  float* stats = (float*)alloc(2560 * 4);  // 5 layers x 4 stripes x 128
  size_t fill_beg = off;
  int* idx0 = (int*)alloc((size_t)B_ * D0_ * HW_ * 4);
  int* idx1 = (int*)alloc((size_t)B_ * D1_ * HW_ * 4);
  int* claim2 = (int*)alloc((size_t)B_ * D2_ * HW_ * 4);
  size_t fill_end = off;
  int* nbr1 = (int*)alloc((size_t)(ng1 + 4) * 432 * 4);
  u32* gmask1 = (u32*)alloc((size_t)(ng1 + 4) * 4);
  int* nbrz1 = (int*)alloc((size_t)cap1 * 3 * 4);
  int* nbrz2 = (int*)alloc((size_t)cap2 * 3 * 4);
  int* coords1 = (int*)alloc((size_t)cap1 * 4 * 4);
  int* coords2 = (int*)alloc((size_t)cap2 * 4 * 4);
  float* xb0 = (float*)alloc((size_t)N * 64 * 4);
  float* xb1 = (float*)alloc((size_t)cap1 * 64 * 4);
  float* xb2 = (float*)alloc((size_t)cap1 * 64 * 4);
  float* xb3 = (float*)alloc((size_t)cap1 * 64 * 4);
  float* xb4 = (float*)alloc((size_t)cap2 * 64 * 4);
  u16* fb = (u16*)alloc((size_t)N * 128 * 2);
  u16* wf0 = (u16*)alloc((size_t)27 * 4 * 2048 * 2);
  u16* wf1a = (u16*)alloc((size_t)27 * 2 * 2048 * 2);
  u16* wf1b = (u16*)alloc((size_t)27 * 2 * 2048 * 2);
  u16* wfz1 = (u16*)alloc((size_t)3 * 2 * 2048 * 2);
  u16* wfz2 = (u16*)alloc((size_t)3 * 2 * 2048 * 2);

  const int* coors = (const int*)d_in[1];
  auto gr = [](long n) { return dim3((unsigned)((n + 255) / 256)); };

  // 1: boot1 (fills + ctrl + stats)
  int nfill16 = (int)((fill_end - fill_beg) / 16);
  k_boot1<<<gr((long)nfill16 + 2563), 256, 0, stream>>>(ctrl, stats,
                                                        (uint4*)(ws + fill_beg), nfill16, N);
  // 2: boot2 (cvt + repacks + scatter)
  long prepTotal = (long)N * 128 + 221184 + 110592 + 110592 + 12288 + 12288 + N;
  k_boot2<<<gr(prepTotal), 256, 0, stream>>>((const float*)d_in[0], (const float*)d_in[3],
                                             (const float*)d_in[9], (const float*)d_in[12],
                                             (const float*)d_in[6], (const float*)d_in[15],
                                             coors, fb, wf0, wf1a, wf1b, wfz1, wfz2, idx0, N);
  // 3: conv0 (LDS nbr + conv + stats0 + claim1)
  k_conv0<<<dim3((N + 63) / 64), 256, 0, stream>>>(fb, coors, idx0, wf0, xb0, N, stats + 0,
                                                   idx1, coords1, nbrz1, ctrl + 1);
  // 4: convz1 (BN0-inline + stats1 + nbr1/gmask1 gen + claim2)
  k_convz<<<dim3((cap1 + 63) / 64), 256, 0, stream>>>(
      xb0, nbrz1, wfz1, stats + 0, ctrl + 0, (const float*)d_in[4], (const float*)d_in[5],
      xb1, ctrl + 1, stats + 512,
      coords1, idx1, D1_, nbr1, gmask1,
      D2_, claim2, coords2, nbrz2, ctrl + 2);
  // 5: conv a (BN1-inline + stats2)
  k_conv1<<<dim3((cap1 + 63) / 64), 256, 0, stream>>>(
      xb1, nbr1, gmask1, wf1a, stats + 512, ctrl + 1, (const float*)d_in[7],
      (const float*)d_in[8], xb2, ctrl + 1, stats + 1024);
  // 6: conv b (BN2-inline + stats3)
  k_conv1<<<dim3((cap1 + 63) / 64), 256, 0, stream>>>(
      xb2, nbr1, gmask1, wf1b, stats + 1024, ctrl + 1, (const float*)d_in[10],
      (const float*)d_in[11], xb3, ctrl + 1, stats + 1536);
  // 7: convz2 (BN3-inline + stats4)
  k_convz<<<dim3((cap2 + 63) / 64), 256, 0, stream>>>(
      xb3, nbrz2, wfz2, stats + 1536, ctrl + 1, (const float*)d_in[13], (const float*)d_in[14],
      xb4, ctrl + 2, stats + 2048,
      nullptr, nullptr, 0, nullptr, nullptr,
      0, nullptr, nullptr, nullptr, nullptr);
  // 8: dense output (BN4-inline)
  long outThreads = (long)B_ * 64 * D2_ * H_ * (W_ / 4);
  k_output<<<gr(outThreads), 256, 0, stream>>>(xb4, ctrl + 2, stats + 2048,
                                               (const float*)d_in[16], (const float*)d_in[17],
                                               claim2, (float*)d_out);
}